// Round 1
// baseline (1339.540 us; speedup 1.0000x reference)
//
#include <hip/hip_runtime.h>

#define LRELU(v) ((v) > 0.f ? (v) : 0.2f * (v))

// ---------------------------------------------------------------------------
// mask decode: input may be bool (1B) or int32 (4B). Sniff deterministically:
// read first 512 words (2048 bytes - in bounds either way). If any word > 1,
// it's packed bytes.
// ---------------------------------------------------------------------------
__global__ void mask_decode_kernel(const unsigned int* __restrict__ mraw,
                                   int* __restrict__ mi) {
    __shared__ int is_u8;
    if (threadIdx.x == 0) {
        int u8 = 0;
        for (int i = 0; i < 512; i++) {
            if (mraw[i] > 1u) { u8 = 1; break; }
        }
        is_u8 = u8;
    }
    __syncthreads();
    if (is_u8) {
        const unsigned char* b8 = (const unsigned char*)mraw;
        for (int i = threadIdx.x; i < 2048; i += blockDim.x) mi[i] = b8[i] ? 1 : 0;
    } else {
        for (int i = threadIdx.x; i < 2048; i += blockDim.x) mi[i] = mraw[i] ? 1 : 0;
    }
}

// ---------------------------------------------------------------------------
// Fused conv1+pool1+conv2+pool2. One block per sequence (2048 blocks).
// x: (2048, 256, 3)  w1: (8,3,128)  w2: (8,128,128)  feat: (2048, 13*128)
// ---------------------------------------------------------------------------
template <int P0, int NP, int J0, int NJ>
__device__ __forceinline__ void conv2_half(const float (*p1)[128],
                                           const float* __restrict__ w2,
                                           float bias2, int ch, long s,
                                           float* __restrict__ feat) {
    float acc[NP];
#pragma unroll
    for (int i = 0; i < NP; i++) acc[i] = bias2;
    for (int cin = 0; cin < 128; cin++) {
        float xv[NP + 7];
#pragma unroll
        for (int q = 0; q < NP + 7; q++) xv[q] = p1[P0 + q][cin];
#pragma unroll
        for (int f = 0; f < 8; f++) {
            float w = w2[(f * 128 + cin) * 128 + ch];
#pragma unroll
            for (int i = 0; i < NP; i++) acc[i] = fmaf(xv[i + f], w, acc[i]);
        }
    }
#pragma unroll
    for (int jj = 0; jj < NJ; jj++) {
        int j = J0 + jj;
        int b0 = j * 4 - P0;  // compile-time after unroll
        float v0 = LRELU(acc[b0 + 0]);
        float v1 = LRELU(acc[b0 + 1]);
        float v2 = LRELU(acc[b0 + 2]);
        float v3 = LRELU(acc[b0 + 3]);
        feat[s * 1664 + j * 128 + ch] = fmaxf(fmaxf(v0, v1), fmaxf(v2, v3));
    }
}

__global__ __launch_bounds__(256) void conv_kernel(
    const float* __restrict__ x, const float* __restrict__ w1,
    const float* __restrict__ b1, const float* __restrict__ w2,
    const float* __restrict__ b2, float* __restrict__ feat) {
    __shared__ float xs[3][256];
    __shared__ float p1[62][128];
    long s = blockIdx.x;
    int tid = threadIdx.x;
    const float* xp = x + s * 768;
    for (int i = tid; i < 768; i += 256) xs[i % 3][i / 3] = xp[i];
    __syncthreads();

    int ch = tid & 127;
    int half = tid >> 7;
    // conv1 weights for this output channel (24 regs)
    float w1r[24];
#pragma unroll
    for (int fc = 0; fc < 24; fc++) w1r[fc] = w1[fc * 128 + ch];
    float bias1 = b1[ch];
    for (int po = half; po < 62; po += 2) {
        int p0 = po * 4;
        float a0 = bias1, a1 = bias1, a2 = bias1, a3 = bias1;
#pragma unroll
        for (int c = 0; c < 3; c++) {
            float xv[11];
#pragma unroll
            for (int q = 0; q < 11; q++) xv[q] = xs[c][p0 + q];
#pragma unroll
            for (int f = 0; f < 8; f++) {
                float w = w1r[f * 3 + c];
                a0 = fmaf(xv[f + 0], w, a0);
                a1 = fmaf(xv[f + 1], w, a1);
                a2 = fmaf(xv[f + 2], w, a2);
                a3 = fmaf(xv[f + 3], w, a3);
            }
        }
        float m01 = fmaxf(LRELU(a0), LRELU(a1));
        float m23 = fmaxf(LRELU(a2), LRELU(a3));
        p1[po][ch] = fmaxf(m01, m23);
    }
    __syncthreads();

    float bias2 = b2[ch];
    if (half == 0)
        conv2_half<0, 28, 0, 7>(p1, w2, bias2, ch, s, feat);
    else
        conv2_half<28, 24, 7, 6>(p1, w2, bias2, ch, s, feat);
}

// ---------------------------------------------------------------------------
// Generic batched fp32 GEMM: C = act(A @ B + bias) * rowmask
// A: (M,K) row-major, B: (K,N) row-major. 64x64 tile, 256 threads, 4x4/thread.
// M % 64 == 0, N % 64 == 0, K % 16 == 0.
// ---------------------------------------------------------------------------
template <int ACT>
__global__ __launch_bounds__(256) void gemm_nn(
    const float* __restrict__ A, long sA, const float* __restrict__ B, long sB,
    const float* __restrict__ bias, const int* __restrict__ qmask,
    float* __restrict__ C, long sC, int M, int N, int K) {
    int bz = blockIdx.z;
    A += (long)bz * sA;
    B += (long)bz * sB;
    C += (long)bz * sC;
    __shared__ __align__(16) float As[16][68];
    __shared__ __align__(16) float Bs[16][68];
    int tid = threadIdx.x;
    int tm = tid >> 4, tn = tid & 15;
    int m0 = blockIdx.y * 64, n0 = blockIdx.x * 64;
    int la_m = tid & 63, la_k = (tid >> 6) * 4;
    int lb_k = tid >> 4, lb_n = (tid & 15) * 4;
    float acc[4][4] = {};
    for (int k0 = 0; k0 < K; k0 += 16) {
        float4 av = *(const float4*)&A[(long)(m0 + la_m) * K + k0 + la_k];
        float4 bv = *(const float4*)&B[(long)(k0 + lb_k) * N + n0 + lb_n];
        As[la_k + 0][la_m] = av.x;
        As[la_k + 1][la_m] = av.y;
        As[la_k + 2][la_m] = av.z;
        As[la_k + 3][la_m] = av.w;
        *(float4*)&Bs[lb_k][lb_n] = bv;
        __syncthreads();
#pragma unroll
        for (int k = 0; k < 16; k++) {
            float4 a4 = *(const float4*)&As[k][tm * 4];
            float4 b4 = *(const float4*)&Bs[k][tn * 4];
            float aa[4] = {a4.x, a4.y, a4.z, a4.w};
            float bb[4] = {b4.x, b4.y, b4.z, b4.w};
#pragma unroll
            for (int i = 0; i < 4; i++)
#pragma unroll
                for (int j = 0; j < 4; j++) acc[i][j] = fmaf(aa[i], bb[j], acc[i][j]);
        }
        __syncthreads();
    }
#pragma unroll
    for (int i = 0; i < 4; i++) {
        int row = m0 + tm * 4 + i;
        float msc = qmask ? (float)qmask[(long)bz * M + row] : 1.f;
#pragma unroll
        for (int j = 0; j < 4; j++) {
            int col = n0 + tn * 4 + j;
            float v = acc[i][j] + (bias ? bias[col] : 0.f);
            if (ACT == 1) v = LRELU(v);
            C[(long)row * N + col] = v * msc;
        }
    }
}

// ---------------------------------------------------------------------------
// scores = h @ h^T with key-mask (-1e9), batched over 4.
// h: (4,512,256)  S: (4,512,512)
// ---------------------------------------------------------------------------
__global__ __launch_bounds__(256) void scores_kernel(
    const float* __restrict__ h, const int* __restrict__ mask,
    float* __restrict__ S) {
    int bz = blockIdx.z;
    const float* A = h + (long)bz * 512 * 256;
    float* C = S + (long)bz * 512 * 512;
    __shared__ __align__(16) float As[16][68];
    __shared__ __align__(16) float Bs[16][68];
    int tid = threadIdx.x;
    int tm = tid >> 4, tn = tid & 15;
    int m0 = blockIdx.y * 64, n0 = blockIdx.x * 64;
    int lr = tid & 63, lk = (tid >> 6) * 4;
    float acc[4][4] = {};
    for (int k0 = 0; k0 < 256; k0 += 16) {
        float4 av = *(const float4*)&A[(long)(m0 + lr) * 256 + k0 + lk];
        float4 bv = *(const float4*)&A[(long)(n0 + lr) * 256 + k0 + lk];
        As[lk + 0][lr] = av.x;
        As[lk + 1][lr] = av.y;
        As[lk + 2][lr] = av.z;
        As[lk + 3][lr] = av.w;
        Bs[lk + 0][lr] = bv.x;
        Bs[lk + 1][lr] = bv.y;
        Bs[lk + 2][lr] = bv.z;
        Bs[lk + 3][lr] = bv.w;
        __syncthreads();
#pragma unroll
        for (int k = 0; k < 16; k++) {
            float4 a4 = *(const float4*)&As[k][tm * 4];
            float4 b4 = *(const float4*)&Bs[k][tn * 4];
            float aa[4] = {a4.x, a4.y, a4.z, a4.w};
            float bb[4] = {b4.x, b4.y, b4.z, b4.w};
#pragma unroll
            for (int i = 0; i < 4; i++)
#pragma unroll
                for (int j = 0; j < 4; j++) acc[i][j] = fmaf(aa[i], bb[j], acc[i][j]);
        }
        __syncthreads();
    }
#pragma unroll
    for (int i = 0; i < 4; i++) {
        int t = m0 + tm * 4 + i;
#pragma unroll
        for (int j = 0; j < 4; j++) {
            int ss = n0 + tn * 4 + j;
            C[(long)t * 512 + ss] = mask[bz * 512 + ss] ? acc[i][j] : -1e9f;
        }
    }
}

// row softmax over 512, block per row
__global__ __launch_bounds__(256) void softmax_kernel(float* __restrict__ S) {
    long row = blockIdx.x;
    float* p = S + row * 512;
    int tid = threadIdx.x;
    __shared__ float red[8];
    float v0 = p[tid], v1 = p[tid + 256];
    float mx = fmaxf(v0, v1);
#pragma unroll
    for (int off = 32; off; off >>= 1) mx = fmaxf(mx, __shfl_down(mx, off));
    if ((tid & 63) == 0) red[tid >> 6] = mx;
    __syncthreads();
    mx = fmaxf(fmaxf(red[0], red[1]), fmaxf(red[2], red[3]));
    float e0 = expf(v0 - mx), e1 = expf(v1 - mx);
    float sm = e0 + e1;
#pragma unroll
    for (int off = 32; off; off >>= 1) sm += __shfl_down(sm, off);
    if ((tid & 63) == 0) red[4 + (tid >> 6)] = sm;
    __syncthreads();
    float inv = 1.f / (red[4] + red[5] + red[6] + red[7]);
    p[tid] = e0 * inv;
    p[tid + 256] = e1 * inv;
}

// ---------------------------------------------------------------------------
// GRU scan. 8 blocks = (4 batches) x (2 directions), 384 threads.
// Thread t owns U column t (128 regs). h broadcast via LDS.
// Masked steps carry state through (and skip the matmul).
// out: (4,512,256), fwd -> [0:128], bwd -> [128:256]
// ---------------------------------------------------------------------------
__global__ __launch_bounds__(384) void gru_kernel(
    const float* __restrict__ xgf, const float* __restrict__ xgb,
    const float* __restrict__ Uf, const float* __restrict__ Ub,
    const float* __restrict__ brf, const float* __restrict__ brb,
    const float* __restrict__ h0f, const float* __restrict__ h0b,
    const int* __restrict__ mask, float* __restrict__ out) {
    int b = blockIdx.x & 3;
    int dir = blockIdx.x >> 2;
    const float* xg = dir ? xgb : xgf;
    const float* U = dir ? Ub : Uf;
    const float* br = dir ? brb : brf;
    const float* h0 = dir ? h0b : h0f;
    int tid = threadIdx.x;
    float u[128];
#pragma unroll
    for (int k = 0; k < 128; k++) u[k] = U[k * 384 + tid];
    float brv = br[tid];
    __shared__ __align__(16) float h[128];
    __shared__ float az[128], ar[128], gx[128], gr[128];
    if (tid < 128) h[tid] = h0[b * 128 + tid];
    __syncthreads();
    for (int step = 0; step < 512; step++) {
        int t = dir ? (511 - step) : step;
        int mt = mask[b * 512 + t];
        long rowoff = (long)(b * 512 + t);
        if (mt) {
            float xt = xg[rowoff * 384 + tid];
            float rg = brv;
#pragma unroll
            for (int k = 0; k < 128; k += 4) {
                float4 hv = *(const float4*)&h[k];
                rg = fmaf(hv.x, u[k + 0], rg);
                rg = fmaf(hv.y, u[k + 1], rg);
                rg = fmaf(hv.z, u[k + 2], rg);
                rg = fmaf(hv.w, u[k + 3], rg);
            }
            if (tid < 128) az[tid] = xt + rg;
            else if (tid < 256) ar[tid - 128] = xt + rg;
            else { gx[tid - 256] = xt; gr[tid - 256] = rg; }
            __syncthreads();
            if (tid < 128) {
                float z = 1.f / (1.f + expf(-az[tid]));
                float r = 1.f / (1.f + expf(-ar[tid]));
                float hh = tanhf(gx[tid] + r * gr[tid]);
                float hn = z * h[tid] + (1.f - z) * hh;
                out[rowoff * 256 + dir * 128 + tid] = hn;
                h[tid] = hn;
            }
            __syncthreads();
        } else {
            if (tid < 128) out[rowoff * 256 + dir * 128 + tid] = h[tid];
        }
    }
}

// final dense 256 -> 1, one wave per row
__global__ __launch_bounds__(256) void final_kernel(
    const float* __restrict__ fc2, const float* __restrict__ w,
    const float* __restrict__ b, float* __restrict__ out) {
    int row = blockIdx.x * 4 + (threadIdx.x >> 6);
    int lane = threadIdx.x & 63;
    const float* a = fc2 + (long)row * 256;
    float acc = 0.f;
#pragma unroll
    for (int i = 0; i < 4; i++) acc = fmaf(a[lane + i * 64], w[lane + i * 64], acc);
#pragma unroll
    for (int off = 32; off; off >>= 1) acc += __shfl_down(acc, off);
    if (lane == 0) out[row] = acc + b[0];
}

// ---------------------------------------------------------------------------
extern "C" void kernel_launch(void* const* d_in, const int* in_sizes, int n_in,
                              void* d_out, int out_size, void* d_ws,
                              size_t ws_size, hipStream_t stream) {
    const float* x = (const float*)d_in[0];
    const unsigned int* mraw = (const unsigned int*)d_in[1];
    const float* s1f = (const float*)d_in[2];
    const float* s1b = (const float*)d_in[3];
    const float* s2f = (const float*)d_in[4];
    const float* s2b = (const float*)d_in[5];
    const float* c1w = (const float*)d_in[6];
    const float* c1b = (const float*)d_in[7];
    const float* c2w = (const float*)d_in[8];
    const float* c2b = (const float*)d_in[9];
    const float* g1fW = (const float*)d_in[10];
    const float* g1fU = (const float*)d_in[11];
    const float* g1fb = (const float*)d_in[12];
    const float* g1bW = (const float*)d_in[13];
    const float* g1bU = (const float*)d_in[14];
    const float* g1bb = (const float*)d_in[15];
    const float* g2fW = (const float*)d_in[16];
    const float* g2fU = (const float*)d_in[17];
    const float* g2fb = (const float*)d_in[18];
    const float* g2bW = (const float*)d_in[19];
    const float* g2bU = (const float*)d_in[20];
    const float* g2bb = (const float*)d_in[21];
    const float* d1w = (const float*)d_in[22];
    const float* d1b = (const float*)d_in[23];
    const float* d2w = (const float*)d_in[24];
    const float* d2b = (const float*)d_in[25];
    const float* d3w = (const float*)d_in[26];
    const float* d3b = (const float*)d_in[27];
    float* out = (float*)d_out;

    float* ws = (float*)d_ws;
    size_t off = 0;
    auto take = [&](size_t n) {
        float* p = ws + off;
        off += (n + 63) & ~(size_t)63;
        return p;
    };
    int* mask_i = (int*)take(2048);
    float* feat = take(2048UL * 1664);
    float* xg1f = take(2048UL * 384);
    float* xg1b = take(2048UL * 384);
    float* gru1 = take(2048UL * 256);
    float* xg2f = take(2048UL * 384);
    float* xg2b = take(2048UL * 384);
    float* gru2 = take(2048UL * 256);
    float* sc = take(4UL * 512 * 512);
    float* attn = take(2048UL * 256);
    float* fc1 = take(2048UL * 256);
    float* fc2 = take(2048UL * 256);

    mask_decode_kernel<<<1, 256, 0, stream>>>(mraw, mask_i);
    conv_kernel<<<2048, 256, 0, stream>>>(x, c1w, c1b, c2w, c2b, feat);

    // GRU layer 1 input projections (+input bias row 0)
    gemm_nn<0><<<dim3(6, 32, 1), 256, 0, stream>>>(feat, 0, g1fW, 0, g1fb, nullptr,
                                                   xg1f, 0, 2048, 384, 1664);
    gemm_nn<0><<<dim3(6, 32, 1), 256, 0, stream>>>(feat, 0, g1bW, 0, g1bb, nullptr,
                                                   xg1b, 0, 2048, 384, 1664);
    gru_kernel<<<8, 384, 0, stream>>>(xg1f, xg1b, g1fU, g1bU, g1fb + 384,
                                      g1bb + 384, s1f, s1b, mask_i, gru1);

    gemm_nn<0><<<dim3(6, 32, 1), 256, 0, stream>>>(gru1, 0, g2fW, 0, g2fb, nullptr,
                                                   xg2f, 0, 2048, 384, 256);
    gemm_nn<0><<<dim3(6, 32, 1), 256, 0, stream>>>(gru1, 0, g2bW, 0, g2bb, nullptr,
                                                   xg2b, 0, 2048, 384, 256);
    gru_kernel<<<8, 384, 0, stream>>>(xg2f, xg2b, g2fU, g2bU, g2fb + 384,
                                      g2bb + 384, s2f, s2b, mask_i, gru2);

    // attention
    scores_kernel<<<dim3(8, 8, 4), 256, 0, stream>>>(gru2, mask_i, sc);
    softmax_kernel<<<2048, 256, 0, stream>>>(sc);
    gemm_nn<0><<<dim3(4, 8, 4), 256, 0, stream>>>(sc, 512L * 512, gru2, 512L * 256,
                                                  nullptr, mask_i, attn, 512L * 256,
                                                  512, 256, 512);

    // dense head
    gemm_nn<1><<<dim3(4, 32, 1), 256, 0, stream>>>(attn, 0, d1w, 0, d1b, nullptr,
                                                   fc1, 0, 2048, 256, 256);
    gemm_nn<1><<<dim3(4, 32, 1), 256, 0, stream>>>(fc1, 0, d2w, 0, d2b, nullptr,
                                                   fc2, 0, 2048, 256, 256);
    final_kernel<<<512, 256, 0, stream>>>(fc2, d3w, d3b, out);
}

// Round 2
// 1266.955 us; speedup vs baseline: 1.0573x; 1.0573x over previous
//
#include <hip/hip_runtime.h>

#define LRELU(v) ((v) > 0.f ? (v) : 0.2f * (v))

typedef float f32x4 __attribute__((ext_vector_type(4)));
typedef __bf16 bf16x8 __attribute__((ext_vector_type(8)));
typedef unsigned short ushort8v __attribute__((ext_vector_type(8)));

__device__ __forceinline__ unsigned short f2bf(float f) {
    unsigned int u = __float_as_uint(f);
    u += 0x7fffu + ((u >> 16) & 1u);
    return (unsigned short)(u >> 16);
}
__device__ __forceinline__ float bf2f(unsigned short h) {
    return __uint_as_float(((unsigned int)h) << 16);
}

// ---------------------------------------------------------------------------
// mask decode: input may be bool (1B) or int32 (4B). Sniff deterministically.
// ---------------------------------------------------------------------------
__global__ void mask_decode_kernel(const unsigned int* __restrict__ mraw,
                                   int* __restrict__ mi) {
    __shared__ int is_u8;
    if (threadIdx.x == 0) {
        int u8 = 0;
        for (int i = 0; i < 512; i++) {
            if (mraw[i] > 1u) { u8 = 1; break; }
        }
        is_u8 = u8;
    }
    __syncthreads();
    if (is_u8) {
        const unsigned char* b8 = (const unsigned char*)mraw;
        for (int i = threadIdx.x; i < 2048; i += blockDim.x) mi[i] = b8[i] ? 1 : 0;
    } else {
        for (int i = threadIdx.x; i < 2048; i += blockDim.x) mi[i] = mraw[i] ? 1 : 0;
    }
}

// ---------------------------------------------------------------------------
// prepack w2 (8,128,128) -> B^T bf16 hi/lo: Bt[c][k], k = f*128+cin (1024)
// ---------------------------------------------------------------------------
__global__ __launch_bounds__(256) void prepack_w2(const float* __restrict__ w2,
                                                  unsigned short* __restrict__ bth,
                                                  unsigned short* __restrict__ btl) {
    int idx = blockIdx.x * 256 + threadIdx.x;  // 131072 total
    int c = idx >> 10, k = idx & 1023;
    float v = w2[k * 128 + c];
    unsigned short hi = f2bf(v);
    unsigned short lo = f2bf(v - bf2f(hi));
    bth[(long)c * 1024 + k] = hi;
    btl[(long)c * 1024 + k] = lo;
}

// ---------------------------------------------------------------------------
// Fused conv1(fp32)+pool1 -> LDS bf16 hi/lo -> conv2 via split-bf16 MFMA +
// fused leaky+pool2. One block (256 thr, 4 waves) per sequence.
// x: (2048,256,3)  w1: (8,3,128)  feat: (2048, 13*128)
// A-frag (16x16x32 bf16): lane l: row = l&15, k = 8*(l>>4)+j (contiguous 8)
// B-frag: lane l: col = l&15, k = 8*(l>>4)+j  -> read from Bt[c][k] rows
// D: lane l: col = l&15, row = 4*(l>>4)+reg  -> pool group in-lane
// ---------------------------------------------------------------------------
__global__ __launch_bounds__(256) void conv_kernel(
    const float* __restrict__ x, const float* __restrict__ w1,
    const float* __restrict__ b1, const unsigned short* __restrict__ bth,
    const unsigned short* __restrict__ btl, const float* __restrict__ b2,
    float* __restrict__ feat) {
    __shared__ float xs[3][256];
    __shared__ __align__(16) unsigned short p1h[72 * 128];
    __shared__ __align__(16) unsigned short p1l[72 * 128];
    long s = blockIdx.x;
    int tid = threadIdx.x;
    const float* xp = x + s * 768;
    for (int i = tid; i < 768; i += 256) xs[i % 3][i / 3] = xp[i];
    // zero the pad rows (62..71) so MFMA padding rows stay finite
    for (int i = tid; i < 10 * 128; i += 256) {
        p1h[62 * 128 + i] = 0;
        p1l[62 * 128 + i] = 0;
    }
    __syncthreads();

    {   // conv1 + pool1, fp32, swizzled bf16 hi/lo store
        int ch = tid & 127;
        int half = tid >> 7;
        float w1r[24];
#pragma unroll
        for (int fc = 0; fc < 24; fc++) w1r[fc] = w1[fc * 128 + ch];
        float bias1 = b1[ch];
        for (int po = half; po < 62; po += 2) {
            int p0 = po * 4;
            float a0 = bias1, a1 = bias1, a2 = bias1, a3 = bias1;
#pragma unroll
            for (int c = 0; c < 3; c++) {
                float xv[11];
#pragma unroll
                for (int q = 0; q < 11; q++) xv[q] = xs[c][p0 + q];
#pragma unroll
                for (int f = 0; f < 8; f++) {
                    float w = w1r[f * 3 + c];
                    a0 = fmaf(xv[f + 0], w, a0);
                    a1 = fmaf(xv[f + 1], w, a1);
                    a2 = fmaf(xv[f + 2], w, a2);
                    a3 = fmaf(xv[f + 3], w, a3);
                }
            }
            float m01 = fmaxf(LRELU(a0), LRELU(a1));
            float m23 = fmaxf(LRELU(a2), LRELU(a3));
            float v = fmaxf(m01, m23);
            unsigned short hi = f2bf(v);
            unsigned short lo = f2bf(v - bf2f(hi));
            int cs = ch ^ ((po & 7) << 3);
            p1h[po * 128 + cs] = hi;
            p1l[po * 128 + cs] = lo;
        }
    }
    __syncthreads();

    // MFMA conv2: M=64 (55 valid), N=128, K=1024. Wave w owns N-tiles {2w,2w+1}.
    const int l = tid & 63, w = tid >> 6;
    const int r = l & 15, g = l >> 4;
    f32x4 acc[4][2];
    const f32x4 zz = {0.f, 0.f, 0.f, 0.f};
#pragma unroll
    for (int m = 0; m < 4; m++) {
        acc[m][0] = zz;
        acc[m][1] = zz;
    }
#pragma unroll 2
    for (int ks = 0; ks < 32; ks++) {
        const int f = ks >> 2;
        const int cin0 = ((ks & 3) << 5) + (g << 3);
        bf16x8 bh[2], bl[2];
#pragma unroll
        for (int n = 0; n < 2; n++) {
            const int c = ((w << 1) + n) * 16 + r;
            const long bo = (long)c * 1024 + (ks << 5) + (g << 3);
            bh[n] = __builtin_bit_cast(bf16x8, *(const ushort8v*)(bth + bo));
            bl[n] = __builtin_bit_cast(bf16x8, *(const ushort8v*)(btl + bo));
        }
        bf16x8 ah[4], al[4];
#pragma unroll
        for (int m = 0; m < 4; m++) {
            const int row = m * 16 + r + f;
            const int col = cin0 ^ ((row & 7) << 3);
            const int off = row * 128 + col;
            ah[m] = __builtin_bit_cast(bf16x8, *(const ushort8v*)(p1h + off));
            al[m] = __builtin_bit_cast(bf16x8, *(const ushort8v*)(p1l + off));
        }
#pragma unroll
        for (int m = 0; m < 4; m++) {
#pragma unroll
            for (int n = 0; n < 2; n++) {
                acc[m][n] = __builtin_amdgcn_mfma_f32_16x16x32_bf16(ah[m], bh[n], acc[m][n], 0, 0, 0);
                acc[m][n] = __builtin_amdgcn_mfma_f32_16x16x32_bf16(ah[m], bl[n], acc[m][n], 0, 0, 0);
                acc[m][n] = __builtin_amdgcn_mfma_f32_16x16x32_bf16(al[m], bh[n], acc[m][n], 0, 0, 0);
            }
        }
    }
    // epilogue: bias + leaky + pool2 (in-lane: regs 0..3 = one pool group)
#pragma unroll
    for (int m = 0; m < 4; m++) {
        const int j = m * 4 + g;
        if (j < 13) {
#pragma unroll
            for (int n = 0; n < 2; n++) {
                const int ch = ((w << 1) + n) * 16 + r;
                const float bias = b2[ch];
                float v0 = LRELU(acc[m][n].x + bias);
                float v1 = LRELU(acc[m][n].y + bias);
                float v2 = LRELU(acc[m][n].z + bias);
                float v3 = LRELU(acc[m][n].w + bias);
                feat[s * 1664 + j * 128 + ch] = fmaxf(fmaxf(v0, v1), fmaxf(v2, v3));
            }
        }
    }
}

// ---------------------------------------------------------------------------
// Generic batched fp32 GEMM: C = act(A @ B + bias) * rowmask
// ---------------------------------------------------------------------------
template <int ACT>
__global__ __launch_bounds__(256) void gemm_nn(
    const float* __restrict__ A, long sA, const float* __restrict__ B, long sB,
    const float* __restrict__ bias, const int* __restrict__ qmask,
    float* __restrict__ C, long sC, int M, int N, int K) {
    int bz = blockIdx.z;
    A += (long)bz * sA;
    B += (long)bz * sB;
    C += (long)bz * sC;
    __shared__ __align__(16) float As[16][68];
    __shared__ __align__(16) float Bs[16][68];
    int tid = threadIdx.x;
    int tm = tid >> 4, tn = tid & 15;
    int m0 = blockIdx.y * 64, n0 = blockIdx.x * 64;
    int la_m = tid & 63, la_k = (tid >> 6) * 4;
    int lb_k = tid >> 4, lb_n = (tid & 15) * 4;
    float acc[4][4] = {};
    for (int k0 = 0; k0 < K; k0 += 16) {
        float4 av = *(const float4*)&A[(long)(m0 + la_m) * K + k0 + la_k];
        float4 bv = *(const float4*)&B[(long)(k0 + lb_k) * N + n0 + lb_n];
        As[la_k + 0][la_m] = av.x;
        As[la_k + 1][la_m] = av.y;
        As[la_k + 2][la_m] = av.z;
        As[la_k + 3][la_m] = av.w;
        *(float4*)&Bs[lb_k][lb_n] = bv;
        __syncthreads();
#pragma unroll
        for (int k = 0; k < 16; k++) {
            float4 a4 = *(const float4*)&As[k][tm * 4];
            float4 b4 = *(const float4*)&Bs[k][tn * 4];
            float aa[4] = {a4.x, a4.y, a4.z, a4.w};
            float bb[4] = {b4.x, b4.y, b4.z, b4.w};
#pragma unroll
            for (int i = 0; i < 4; i++)
#pragma unroll
                for (int j = 0; j < 4; j++) acc[i][j] = fmaf(aa[i], bb[j], acc[i][j]);
        }
        __syncthreads();
    }
#pragma unroll
    for (int i = 0; i < 4; i++) {
        int row = m0 + tm * 4 + i;
        float msc = qmask ? (float)qmask[(long)bz * M + row] : 1.f;
#pragma unroll
        for (int j = 0; j < 4; j++) {
            int col = n0 + tn * 4 + j;
            float v = acc[i][j] + (bias ? bias[col] : 0.f);
            if (ACT == 1) v = LRELU(v);
            C[(long)row * N + col] = v * msc;
        }
    }
}

// ---------------------------------------------------------------------------
// scores = h @ h^T with key-mask (-1e9), batched over 4.
// ---------------------------------------------------------------------------
__global__ __launch_bounds__(256) void scores_kernel(
    const float* __restrict__ h, const int* __restrict__ mask,
    float* __restrict__ S) {
    int bz = blockIdx.z;
    const float* A = h + (long)bz * 512 * 256;
    float* C = S + (long)bz * 512 * 512;
    __shared__ __align__(16) float As[16][68];
    __shared__ __align__(16) float Bs[16][68];
    int tid = threadIdx.x;
    int tm = tid >> 4, tn = tid & 15;
    int m0 = blockIdx.y * 64, n0 = blockIdx.x * 64;
    int lr = tid & 63, lk = (tid >> 6) * 4;
    float acc[4][4] = {};
    for (int k0 = 0; k0 < 256; k0 += 16) {
        float4 av = *(const float4*)&A[(long)(m0 + lr) * 256 + k0 + lk];
        float4 bv = *(const float4*)&A[(long)(n0 + lr) * 256 + k0 + lk];
        As[lk + 0][lr] = av.x;
        As[lk + 1][lr] = av.y;
        As[lk + 2][lr] = av.z;
        As[lk + 3][lr] = av.w;
        Bs[lk + 0][lr] = bv.x;
        Bs[lk + 1][lr] = bv.y;
        Bs[lk + 2][lr] = bv.z;
        Bs[lk + 3][lr] = bv.w;
        __syncthreads();
#pragma unroll
        for (int k = 0; k < 16; k++) {
            float4 a4 = *(const float4*)&As[k][tm * 4];
            float4 b4 = *(const float4*)&Bs[k][tn * 4];
            float aa[4] = {a4.x, a4.y, a4.z, a4.w};
            float bb[4] = {b4.x, b4.y, b4.z, b4.w};
#pragma unroll
            for (int i = 0; i < 4; i++)
#pragma unroll
                for (int j = 0; j < 4; j++) acc[i][j] = fmaf(aa[i], bb[j], acc[i][j]);
        }
        __syncthreads();
    }
#pragma unroll
    for (int i = 0; i < 4; i++) {
        int t = m0 + tm * 4 + i;
#pragma unroll
        for (int j = 0; j < 4; j++) {
            int ss = n0 + tn * 4 + j;
            C[(long)t * 512 + ss] = mask[bz * 512 + ss] ? acc[i][j] : -1e9f;
        }
    }
}

// row softmax over 512, block per row
__global__ __launch_bounds__(256) void softmax_kernel(float* __restrict__ S) {
    long row = blockIdx.x;
    float* p = S + row * 512;
    int tid = threadIdx.x;
    __shared__ float red[8];
    float v0 = p[tid], v1 = p[tid + 256];
    float mx = fmaxf(v0, v1);
#pragma unroll
    for (int off = 32; off; off >>= 1) mx = fmaxf(mx, __shfl_down(mx, off));
    if ((tid & 63) == 0) red[tid >> 6] = mx;
    __syncthreads();
    mx = fmaxf(fmaxf(red[0], red[1]), fmaxf(red[2], red[3]));
    float e0 = expf(v0 - mx), e1 = expf(v1 - mx);
    float sm = e0 + e1;
#pragma unroll
    for (int off = 32; off; off >>= 1) sm += __shfl_down(sm, off);
    if ((tid & 63) == 0) red[4 + (tid >> 6)] = sm;
    __syncthreads();
    float inv = 1.f / (red[4] + red[5] + red[6] + red[7]);
    p[tid] = e0 * inv;
    p[tid + 256] = e1 * inv;
}

// ---------------------------------------------------------------------------
// GRU scan. 8 blocks = (batch) x (dir), 768 threads = 12 waves (3/SIMD).
// 2 threads per U-column (k-split halves), pair-reduce via shfl_xor(1).
// Next-step xt prefetched to hide L2/L3 latency on the serial chain.
// ---------------------------------------------------------------------------
__global__ __launch_bounds__(768) void gru_kernel(
    const float* __restrict__ xgf, const float* __restrict__ xgb,
    const float* __restrict__ Uf, const float* __restrict__ Ub,
    const float* __restrict__ brf, const float* __restrict__ brb,
    const float* __restrict__ h0f, const float* __restrict__ h0b,
    const int* __restrict__ mask, float* __restrict__ out) {
    int b = blockIdx.x & 3;
    int dir = blockIdx.x >> 2;
    const float* xg = dir ? xgb : xgf;
    const float* U = dir ? Ub : Uf;
    const float* br = dir ? brb : brf;
    const float* h0 = dir ? h0b : h0f;
    int tid = threadIdx.x;
    int col = tid >> 1, half = tid & 1;
    float u[64];
#pragma unroll
    for (int k = 0; k < 64; k++) u[k] = U[(half * 64 + k) * 384 + col];
    float brv = br[col];
    __shared__ __align__(16) float h[128];
    __shared__ float az[128], ar[128], gx[128], gr[128];
    if (tid < 128) h[tid] = h0[b * 128 + tid];
    __syncthreads();
    int t0 = dir ? 511 : 0;
    float xt = xg[(long)(b * 512 + t0) * 384 + col];
    for (int step = 0; step < 512; step++) {
        int t = dir ? (511 - step) : step;
        int tn = dir ? (t - 1) : (t + 1);
        float xt_next = (step < 511) ? xg[(long)(b * 512 + tn) * 384 + col] : 0.f;
        int mt = mask[b * 512 + t];
        long rowoff = (long)(b * 512 + t);
        if (mt) {
            const float* hh = h + half * 64;
            float rg = 0.f;
#pragma unroll
            for (int k = 0; k < 64; k += 4) {
                float4 hv = *(const float4*)&hh[k];
                rg = fmaf(hv.x, u[k + 0], rg);
                rg = fmaf(hv.y, u[k + 1], rg);
                rg = fmaf(hv.z, u[k + 2], rg);
                rg = fmaf(hv.w, u[k + 3], rg);
            }
            rg += __shfl_xor(rg, 1);
            rg += brv;
            if (half == 0) {
                if (col < 128) az[col] = xt + rg;
                else if (col < 256) ar[col - 128] = xt + rg;
                else { gx[col - 256] = xt; gr[col - 256] = rg; }
            }
            __syncthreads();
            if (tid < 128) {
                float z = 1.f / (1.f + expf(-az[tid]));
                float r_ = 1.f / (1.f + expf(-ar[tid]));
                float hhv = tanhf(gx[tid] + r_ * gr[tid]);
                float hn = z * h[tid] + (1.f - z) * hhv;
                out[rowoff * 256 + dir * 128 + tid] = hn;
                h[tid] = hn;
            }
            __syncthreads();
        } else {
            if (tid < 128) out[rowoff * 256 + dir * 128 + tid] = h[tid];
        }
        xt = xt_next;
    }
}

// final dense 256 -> 1, one wave per row
__global__ __launch_bounds__(256) void final_kernel(
    const float* __restrict__ fc2, const float* __restrict__ w,
    const float* __restrict__ b, float* __restrict__ out) {
    int row = blockIdx.x * 4 + (threadIdx.x >> 6);
    int lane = threadIdx.x & 63;
    const float* a = fc2 + (long)row * 256;
    float acc = 0.f;
#pragma unroll
    for (int i = 0; i < 4; i++) acc = fmaf(a[lane + i * 64], w[lane + i * 64], acc);
#pragma unroll
    for (int off = 32; off; off >>= 1) acc += __shfl_down(acc, off);
    if (lane == 0) out[row] = acc + b[0];
}

// ---------------------------------------------------------------------------
extern "C" void kernel_launch(void* const* d_in, const int* in_sizes, int n_in,
                              void* d_out, int out_size, void* d_ws,
                              size_t ws_size, hipStream_t stream) {
    const float* x = (const float*)d_in[0];
    const unsigned int* mraw = (const unsigned int*)d_in[1];
    const float* s1f = (const float*)d_in[2];
    const float* s1b = (const float*)d_in[3];
    const float* s2f = (const float*)d_in[4];
    const float* s2b = (const float*)d_in[5];
    const float* c1w = (const float*)d_in[6];
    const float* c1b = (const float*)d_in[7];
    const float* c2w = (const float*)d_in[8];
    const float* c2b = (const float*)d_in[9];
    const float* g1fW = (const float*)d_in[10];
    const float* g1fU = (const float*)d_in[11];
    const float* g1fb = (const float*)d_in[12];
    const float* g1bW = (const float*)d_in[13];
    const float* g1bU = (const float*)d_in[14];
    const float* g1bb = (const float*)d_in[15];
    const float* g2fW = (const float*)d_in[16];
    const float* g2fU = (const float*)d_in[17];
    const float* g2fb = (const float*)d_in[18];
    const float* g2bW = (const float*)d_in[19];
    const float* g2bU = (const float*)d_in[20];
    const float* g2bb = (const float*)d_in[21];
    const float* d1w = (const float*)d_in[22];
    const float* d1b = (const float*)d_in[23];
    const float* d2w = (const float*)d_in[24];
    const float* d2b = (const float*)d_in[25];
    const float* d3w = (const float*)d_in[26];
    const float* d3b = (const float*)d_in[27];
    float* out = (float*)d_out;

    float* ws = (float*)d_ws;
    size_t off = 0;
    auto take = [&](size_t n) {
        float* p = ws + off;
        off += (n + 63) & ~(size_t)63;
        return p;
    };
    int* mask_i = (int*)take(2048);
    float* feat = take(2048UL * 1664);
    float* xg1f = take(2048UL * 384);
    float* xg1b = take(2048UL * 384);
    float* gru1 = take(2048UL * 256);
    float* xg2f = take(2048UL * 384);
    float* xg2b = take(2048UL * 384);
    float* gru2 = take(2048UL * 256);
    float* sc = take(4UL * 512 * 512);
    float* attn = take(2048UL * 256);
    float* fc1 = take(2048UL * 256);
    float* fc2 = take(2048UL * 256);
    unsigned short* bth = (unsigned short*)take(65536);  // 128x1024 ushort
    unsigned short* btl = (unsigned short*)take(65536);

    mask_decode_kernel<<<1, 256, 0, stream>>>(mraw, mask_i);
    prepack_w2<<<512, 256, 0, stream>>>(c2w, bth, btl);
    conv_kernel<<<2048, 256, 0, stream>>>(x, c1w, c1b, bth, btl, c2b, feat);

    // GRU layer 1 input projections (+input bias row 0)
    gemm_nn<0><<<dim3(6, 32, 1), 256, 0, stream>>>(feat, 0, g1fW, 0, g1fb, nullptr,
                                                   xg1f, 0, 2048, 384, 1664);
    gemm_nn<0><<<dim3(6, 32, 1), 256, 0, stream>>>(feat, 0, g1bW, 0, g1bb, nullptr,
                                                   xg1b, 0, 2048, 384, 1664);
    gru_kernel<<<8, 768, 0, stream>>>(xg1f, xg1b, g1fU, g1bU, g1fb + 384,
                                      g1bb + 384, s1f, s1b, mask_i, gru1);

    gemm_nn<0><<<dim3(6, 32, 1), 256, 0, stream>>>(gru1, 0, g2fW, 0, g2fb, nullptr,
                                                   xg2f, 0, 2048, 384, 256);
    gemm_nn<0><<<dim3(6, 32, 1), 256, 0, stream>>>(gru1, 0, g2bW, 0, g2bb, nullptr,
                                                   xg2b, 0, 2048, 384, 256);
    gru_kernel<<<8, 768, 0, stream>>>(xg2f, xg2b, g2fU, g2bU, g2fb + 384,
                                      g2bb + 384, s2f, s2b, mask_i, gru2);

    // attention
    scores_kernel<<<dim3(8, 8, 4), 256, 0, stream>>>(gru2, mask_i, sc);
    softmax_kernel<<<2048, 256, 0, stream>>>(sc);
    gemm_nn<0><<<dim3(4, 8, 4), 256, 0, stream>>>(sc, 512L * 512, gru2, 512L * 256,
                                                  nullptr, mask_i, attn, 512L * 256,
                                                  512, 256, 512);

    // dense head
    gemm_nn<1><<<dim3(4, 32, 1), 256, 0, stream>>>(attn, 0, d1w, 0, d1b, nullptr,
                                                   fc1, 0, 2048, 256, 256);
    gemm_nn<1><<<dim3(4, 32, 1), 256, 0, stream>>>(fc1, 0, d2w, 0, d2b, nullptr,
                                                   fc2, 0, 2048, 256, 256);
    final_kernel<<<512, 256, 0, stream>>>(fc2, d3w, d3b, out);
}

// Round 3
// 1160.189 us; speedup vs baseline: 1.1546x; 1.0920x over previous
//
#include <hip/hip_runtime.h>

#define LRELU(v) ((v) > 0.f ? (v) : 0.2f * (v))

typedef float f32x4 __attribute__((ext_vector_type(4)));
typedef __bf16 bf16x8 __attribute__((ext_vector_type(8)));
typedef unsigned short ushort8v __attribute__((ext_vector_type(8)));

__device__ __forceinline__ unsigned short f2bf(float f) {
    unsigned int u = __float_as_uint(f);
    u += 0x7fffu + ((u >> 16) & 1u);
    return (unsigned short)(u >> 16);
}
__device__ __forceinline__ float bf2f(unsigned short h) {
    return __uint_as_float(((unsigned int)h) << 16);
}
__device__ __forceinline__ float sigmoid_fast(float x) {
    float e = __builtin_amdgcn_exp2f(-x * 1.442695041f);
    return __builtin_amdgcn_rcpf(1.f + e);
}
__device__ __forceinline__ float tanh_fast(float x) {
    float e = __builtin_amdgcn_exp2f(x * 2.885390082f);  // e^(2x)
    return 1.f - 2.f * __builtin_amdgcn_rcpf(e + 1.f);
}

// ---------------------------------------------------------------------------
// mask decode: input may be bool (1B) or int32 (4B). Sniff deterministically.
// ---------------------------------------------------------------------------
__global__ void mask_decode_kernel(const unsigned int* __restrict__ mraw,
                                   int* __restrict__ mi) {
    __shared__ int is_u8;
    if (threadIdx.x == 0) {
        int u8 = 0;
        for (int i = 0; i < 512; i++) {
            if (mraw[i] > 1u) { u8 = 1; break; }
        }
        is_u8 = u8;
    }
    __syncthreads();
    if (is_u8) {
        const unsigned char* b8 = (const unsigned char*)mraw;
        for (int i = threadIdx.x; i < 2048; i += blockDim.x) mi[i] = b8[i] ? 1 : 0;
    } else {
        for (int i = threadIdx.x; i < 2048; i += blockDim.x) mi[i] = mraw[i] ? 1 : 0;
    }
}

// ---------------------------------------------------------------------------
// prepack w2 (8,128,128) -> B^T bf16 hi/lo: Bt[c][k], k = f*128+cin (1024)
// ---------------------------------------------------------------------------
__global__ __launch_bounds__(256) void prepack_w2(const float* __restrict__ w2,
                                                  unsigned short* __restrict__ bth,
                                                  unsigned short* __restrict__ btl) {
    int idx = blockIdx.x * 256 + threadIdx.x;  // 131072 total
    int c = idx >> 10, k = idx & 1023;
    float v = w2[k * 128 + c];
    unsigned short hi = f2bf(v);
    unsigned short lo = f2bf(v - bf2f(hi));
    bth[(long)c * 1024 + k] = hi;
    btl[(long)c * 1024 + k] = lo;
}

// ---------------------------------------------------------------------------
// Fused conv1(fp32)+pool1 -> LDS bf16 hi/lo -> conv2 via split-bf16 MFMA +
// fused leaky+pool2. One block (256 thr, 4 waves) per sequence.
// ---------------------------------------------------------------------------
__global__ __launch_bounds__(256) void conv_kernel(
    const float* __restrict__ x, const float* __restrict__ w1,
    const float* __restrict__ b1, const unsigned short* __restrict__ bth,
    const unsigned short* __restrict__ btl, const float* __restrict__ b2,
    float* __restrict__ feat) {
    __shared__ float xs[3][256];
    __shared__ __align__(16) unsigned short p1h[72 * 128];
    __shared__ __align__(16) unsigned short p1l[72 * 128];
    long s = blockIdx.x;
    int tid = threadIdx.x;
    const float* xp = x + s * 768;
    for (int i = tid; i < 768; i += 256) xs[i % 3][i / 3] = xp[i];
    for (int i = tid; i < 10 * 128; i += 256) {
        p1h[62 * 128 + i] = 0;
        p1l[62 * 128 + i] = 0;
    }
    __syncthreads();

    {   // conv1 + pool1, fp32, swizzled bf16 hi/lo store
        int ch = tid & 127;
        int half = tid >> 7;
        float w1r[24];
#pragma unroll
        for (int fc = 0; fc < 24; fc++) w1r[fc] = w1[fc * 128 + ch];
        float bias1 = b1[ch];
        for (int po = half; po < 62; po += 2) {
            int p0 = po * 4;
            float a0 = bias1, a1 = bias1, a2 = bias1, a3 = bias1;
#pragma unroll
            for (int c = 0; c < 3; c++) {
                float xv[11];
#pragma unroll
                for (int q = 0; q < 11; q++) xv[q] = xs[c][p0 + q];
#pragma unroll
                for (int f = 0; f < 8; f++) {
                    float w = w1r[f * 3 + c];
                    a0 = fmaf(xv[f + 0], w, a0);
                    a1 = fmaf(xv[f + 1], w, a1);
                    a2 = fmaf(xv[f + 2], w, a2);
                    a3 = fmaf(xv[f + 3], w, a3);
                }
            }
            float m01 = fmaxf(LRELU(a0), LRELU(a1));
            float m23 = fmaxf(LRELU(a2), LRELU(a3));
            float v = fmaxf(m01, m23);
            unsigned short hi = f2bf(v);
            unsigned short lo = f2bf(v - bf2f(hi));
            int cs = ch ^ ((po & 7) << 3);
            p1h[po * 128 + cs] = hi;
            p1l[po * 128 + cs] = lo;
        }
    }
    __syncthreads();

    // MFMA conv2: M=64 (55 valid), N=128, K=1024. Wave w owns N-tiles {2w,2w+1}.
    const int l = tid & 63, w = tid >> 6;
    const int r = l & 15, g = l >> 4;
    f32x4 acc[4][2];
    const f32x4 zz = {0.f, 0.f, 0.f, 0.f};
#pragma unroll
    for (int m = 0; m < 4; m++) {
        acc[m][0] = zz;
        acc[m][1] = zz;
    }
#pragma unroll 2
    for (int ks = 0; ks < 32; ks++) {
        const int f = ks >> 2;
        const int cin0 = ((ks & 3) << 5) + (g << 3);
        bf16x8 bh[2], bl[2];
#pragma unroll
        for (int n = 0; n < 2; n++) {
            const int c = ((w << 1) + n) * 16 + r;
            const long bo = (long)c * 1024 + (ks << 5) + (g << 3);
            bh[n] = __builtin_bit_cast(bf16x8, *(const ushort8v*)(bth + bo));
            bl[n] = __builtin_bit_cast(bf16x8, *(const ushort8v*)(btl + bo));
        }
        bf16x8 ah[4], al[4];
#pragma unroll
        for (int m = 0; m < 4; m++) {
            const int row = m * 16 + r + f;
            const int col = cin0 ^ ((row & 7) << 3);
            const int off = row * 128 + col;
            ah[m] = __builtin_bit_cast(bf16x8, *(const ushort8v*)(p1h + off));
            al[m] = __builtin_bit_cast(bf16x8, *(const ushort8v*)(p1l + off));
        }
#pragma unroll
        for (int m = 0; m < 4; m++) {
#pragma unroll
            for (int n = 0; n < 2; n++) {
                acc[m][n] = __builtin_amdgcn_mfma_f32_16x16x32_bf16(ah[m], bh[n], acc[m][n], 0, 0, 0);
                acc[m][n] = __builtin_amdgcn_mfma_f32_16x16x32_bf16(ah[m], bl[n], acc[m][n], 0, 0, 0);
                acc[m][n] = __builtin_amdgcn_mfma_f32_16x16x32_bf16(al[m], bh[n], acc[m][n], 0, 0, 0);
            }
        }
    }
#pragma unroll
    for (int m = 0; m < 4; m++) {
        const int j = m * 4 + g;
        if (j < 13) {
#pragma unroll
            for (int n = 0; n < 2; n++) {
                const int ch = ((w << 1) + n) * 16 + r;
                const float bias = b2[ch];
                float v0 = LRELU(acc[m][n].x + bias);
                float v1 = LRELU(acc[m][n].y + bias);
                float v2 = LRELU(acc[m][n].z + bias);
                float v3 = LRELU(acc[m][n].w + bias);
                feat[s * 1664 + j * 128 + ch] = fmaxf(fmaxf(v0, v1), fmaxf(v2, v3));
            }
        }
    }
}

// ---------------------------------------------------------------------------
// Generic batched fp32 GEMM: C = act(A @ B + bias) * rowmask
// ---------------------------------------------------------------------------
template <int ACT>
__global__ __launch_bounds__(256) void gemm_nn(
    const float* __restrict__ A, long sA, const float* __restrict__ B, long sB,
    const float* __restrict__ bias, const int* __restrict__ qmask,
    float* __restrict__ C, long sC, int M, int N, int K) {
    int bz = blockIdx.z;
    A += (long)bz * sA;
    B += (long)bz * sB;
    C += (long)bz * sC;
    __shared__ __align__(16) float As[16][68];
    __shared__ __align__(16) float Bs[16][68];
    int tid = threadIdx.x;
    int tm = tid >> 4, tn = tid & 15;
    int m0 = blockIdx.y * 64, n0 = blockIdx.x * 64;
    int la_m = tid & 63, la_k = (tid >> 6) * 4;
    int lb_k = tid >> 4, lb_n = (tid & 15) * 4;
    float acc[4][4] = {};
    for (int k0 = 0; k0 < K; k0 += 16) {
        float4 av = *(const float4*)&A[(long)(m0 + la_m) * K + k0 + la_k];
        float4 bv = *(const float4*)&B[(long)(k0 + lb_k) * N + n0 + lb_n];
        As[la_k + 0][la_m] = av.x;
        As[la_k + 1][la_m] = av.y;
        As[la_k + 2][la_m] = av.z;
        As[la_k + 3][la_m] = av.w;
        *(float4*)&Bs[lb_k][lb_n] = bv;
        __syncthreads();
#pragma unroll
        for (int k = 0; k < 16; k++) {
            float4 a4 = *(const float4*)&As[k][tm * 4];
            float4 b4 = *(const float4*)&Bs[k][tn * 4];
            float aa[4] = {a4.x, a4.y, a4.z, a4.w};
            float bb[4] = {b4.x, b4.y, b4.z, b4.w};
#pragma unroll
            for (int i = 0; i < 4; i++)
#pragma unroll
                for (int j = 0; j < 4; j++) acc[i][j] = fmaf(aa[i], bb[j], acc[i][j]);
        }
        __syncthreads();
    }
#pragma unroll
    for (int i = 0; i < 4; i++) {
        int row = m0 + tm * 4 + i;
        float msc = qmask ? (float)qmask[(long)bz * M + row] : 1.f;
#pragma unroll
        for (int j = 0; j < 4; j++) {
            int col = n0 + tn * 4 + j;
            float v = acc[i][j] + (bias ? bias[col] : 0.f);
            if (ACT == 1) v = LRELU(v);
            C[(long)row * N + col] = v * msc;
        }
    }
}

// ---------------------------------------------------------------------------
// scores = h @ h^T with key-mask (-1e9), batched over 4.
// ---------------------------------------------------------------------------
__global__ __launch_bounds__(256) void scores_kernel(
    const float* __restrict__ h, const int* __restrict__ mask,
    float* __restrict__ S) {
    int bz = blockIdx.z;
    const float* A = h + (long)bz * 512 * 256;
    float* C = S + (long)bz * 512 * 512;
    __shared__ __align__(16) float As[16][68];
    __shared__ __align__(16) float Bs[16][68];
    int tid = threadIdx.x;
    int tm = tid >> 4, tn = tid & 15;
    int m0 = blockIdx.y * 64, n0 = blockIdx.x * 64;
    int lr = tid & 63, lk = (tid >> 6) * 4;
    float acc[4][4] = {};
    for (int k0 = 0; k0 < 256; k0 += 16) {
        float4 av = *(const float4*)&A[(long)(m0 + lr) * 256 + k0 + lk];
        float4 bv = *(const float4*)&A[(long)(n0 + lr) * 256 + k0 + lk];
        As[lk + 0][lr] = av.x;
        As[lk + 1][lr] = av.y;
        As[lk + 2][lr] = av.z;
        As[lk + 3][lr] = av.w;
        Bs[lk + 0][lr] = bv.x;
        Bs[lk + 1][lr] = bv.y;
        Bs[lk + 2][lr] = bv.z;
        Bs[lk + 3][lr] = bv.w;
        __syncthreads();
#pragma unroll
        for (int k = 0; k < 16; k++) {
            float4 a4 = *(const float4*)&As[k][tm * 4];
            float4 b4 = *(const float4*)&Bs[k][tn * 4];
            float aa[4] = {a4.x, a4.y, a4.z, a4.w};
            float bb[4] = {b4.x, b4.y, b4.z, b4.w};
#pragma unroll
            for (int i = 0; i < 4; i++)
#pragma unroll
                for (int j = 0; j < 4; j++) acc[i][j] = fmaf(aa[i], bb[j], acc[i][j]);
        }
        __syncthreads();
    }
#pragma unroll
    for (int i = 0; i < 4; i++) {
        int t = m0 + tm * 4 + i;
#pragma unroll
        for (int j = 0; j < 4; j++) {
            int ss = n0 + tn * 4 + j;
            C[(long)t * 512 + ss] = mask[bz * 512 + ss] ? acc[i][j] : -1e9f;
        }
    }
}

// row softmax over 512, block per row
__global__ __launch_bounds__(256) void softmax_kernel(float* __restrict__ S) {
    long row = blockIdx.x;
    float* p = S + row * 512;
    int tid = threadIdx.x;
    __shared__ float red[8];
    float v0 = p[tid], v1 = p[tid + 256];
    float mx = fmaxf(v0, v1);
#pragma unroll
    for (int off = 32; off; off >>= 1) mx = fmaxf(mx, __shfl_down(mx, off));
    if ((tid & 63) == 0) red[tid >> 6] = mx;
    __syncthreads();
    mx = fmaxf(fmaxf(red[0], red[1]), fmaxf(red[2], red[3]));
    float e0 = expf(v0 - mx), e1 = expf(v1 - mx);
    float sm = e0 + e1;
#pragma unroll
    for (int off = 32; off; off >>= 1) sm += __shfl_down(sm, off);
    if ((tid & 63) == 0) red[4 + (tid >> 6)] = sm;
    __syncthreads();
    float inv = 1.f / (red[4] + red[5] + red[6] + red[7]);
    p[tid] = e0 * inv;
    p[tid + 256] = e1 * inv;
}

// ---------------------------------------------------------------------------
// GRU scan. 8 blocks = (batch) x (dir), 768 threads = 12 waves.
// tid -> gate = tid>>8 (z,r,h), cp = (tid&255)>>1 (column 0..127), half=tid&1
// (K-split). Mask preloaded as 8x u64 bitmask (ballot). Sigmoids in stage A
// (parallel), single fast tanh in stage B. Fast exp2/rcp transcendentals.
// ---------------------------------------------------------------------------
__global__ __launch_bounds__(768) void gru_kernel(
    const float* __restrict__ xgf, const float* __restrict__ xgb,
    const float* __restrict__ Uf, const float* __restrict__ Ub,
    const float* __restrict__ brf, const float* __restrict__ brb,
    const float* __restrict__ h0f, const float* __restrict__ h0b,
    const int* __restrict__ mask, float* __restrict__ out) {
    int b = blockIdx.x & 3;
    int dir = blockIdx.x >> 2;
    const float* xg = dir ? xgb : xgf;
    const float* U = dir ? Ub : Uf;
    const float* br = dir ? brb : brf;
    const float* h0 = dir ? h0b : h0f;
    int tid = threadIdx.x;
    int gate = tid >> 8;
    int cp = (tid & 255) >> 1;
    int half = tid & 1;
    int ucol = gate * 128 + cp;
    float u[64];
#pragma unroll
    for (int k = 0; k < 64; k++) u[k] = U[(half * 64 + k) * 384 + ucol];
    float brv = br[ucol];
    __shared__ __align__(16) float h[128];
    __shared__ float zs[128], rs[128], gxv[128], grv[128];
    __shared__ unsigned long long mwords[8];
    if (tid < 128) h[tid] = h0[b * 128 + tid];
    if (tid < 64) {
#pragma unroll
        for (int w = 0; w < 8; w++) {
            int idx = w * 64 + tid;
            int t = dir ? (511 - idx) : idx;
            unsigned long long bm = __ballot(mask[b * 512 + t] != 0);
            if (tid == 0) mwords[w] = bm;
        }
    }
    __syncthreads();
    int t0 = dir ? 511 : 0;
    float xt = xg[(long)(b * 512 + t0) * 384 + ucol];
#pragma unroll 1
    for (int w = 0; w < 8; w++) {
        unsigned long long mw = mwords[w];
#pragma unroll 1
        for (int i = 0; i < 64; i++) {
            int step = w * 64 + i;
            int t = dir ? (511 - step) : step;
            int tnx = dir ? (t - 1) : (t + 1);
            float xt_next = (step < 511) ? xg[(long)(b * 512 + tnx) * 384 + ucol] : 0.f;
            int mt = (int)(mw & 1ull);
            mw >>= 1;
            long rowoff = (long)(b * 512 + t);
            if (mt) {
                const float* hh = h + half * 64;
                float a0 = 0.f, a1 = 0.f, a2 = 0.f, a3 = 0.f;
#pragma unroll
                for (int k = 0; k < 64; k += 4) {
                    float4 hv = *(const float4*)&hh[k];
                    a0 = fmaf(hv.x, u[k + 0], a0);
                    a1 = fmaf(hv.y, u[k + 1], a1);
                    a2 = fmaf(hv.z, u[k + 2], a2);
                    a3 = fmaf(hv.w, u[k + 3], a3);
                }
                float rg = (a0 + a1) + (a2 + a3);
                rg += __shfl_xor(rg, 1);
                rg += brv;
                if (half == 0) {
                    if (gate == 0) zs[cp] = sigmoid_fast(xt + rg);
                    else if (gate == 1) rs[cp] = sigmoid_fast(xt + rg);
                    else { gxv[cp] = xt; grv[cp] = rg; }
                }
                __syncthreads();
                if (tid < 128) {
                    float z = zs[tid], r_ = rs[tid];
                    float hhv = tanh_fast(fmaf(r_, grv[tid], gxv[tid]));
                    float hv = h[tid];
                    float hn = fmaf(z, hv - hhv, hhv);
                    out[rowoff * 256 + dir * 128 + tid] = hn;
                    h[tid] = hn;
                }
                __syncthreads();
            } else {
                if (tid < 128) out[rowoff * 256 + dir * 128 + tid] = h[tid];
            }
            xt = xt_next;
        }
    }
}

// final dense 256 -> 1, one wave per row
__global__ __launch_bounds__(256) void final_kernel(
    const float* __restrict__ fc2, const float* __restrict__ w,
    const float* __restrict__ b, float* __restrict__ out) {
    int row = blockIdx.x * 4 + (threadIdx.x >> 6);
    int lane = threadIdx.x & 63;
    const float* a = fc2 + (long)row * 256;
    float acc = 0.f;
#pragma unroll
    for (int i = 0; i < 4; i++) acc = fmaf(a[lane + i * 64], w[lane + i * 64], acc);
#pragma unroll
    for (int off = 32; off; off >>= 1) acc += __shfl_down(acc, off);
    if (lane == 0) out[row] = acc + b[0];
}

// ---------------------------------------------------------------------------
extern "C" void kernel_launch(void* const* d_in, const int* in_sizes, int n_in,
                              void* d_out, int out_size, void* d_ws,
                              size_t ws_size, hipStream_t stream) {
    const float* x = (const float*)d_in[0];
    const unsigned int* mraw = (const unsigned int*)d_in[1];
    const float* s1f = (const float*)d_in[2];
    const float* s1b = (const float*)d_in[3];
    const float* s2f = (const float*)d_in[4];
    const float* s2b = (const float*)d_in[5];
    const float* c1w = (const float*)d_in[6];
    const float* c1b = (const float*)d_in[7];
    const float* c2w = (const float*)d_in[8];
    const float* c2b = (const float*)d_in[9];
    const float* g1fW = (const float*)d_in[10];
    const float* g1fU = (const float*)d_in[11];
    const float* g1fb = (const float*)d_in[12];
    const float* g1bW = (const float*)d_in[13];
    const float* g1bU = (const float*)d_in[14];
    const float* g1bb = (const float*)d_in[15];
    const float* g2fW = (const float*)d_in[16];
    const float* g2fU = (const float*)d_in[17];
    const float* g2fb = (const float*)d_in[18];
    const float* g2bW = (const float*)d_in[19];
    const float* g2bU = (const float*)d_in[20];
    const float* g2bb = (const float*)d_in[21];
    const float* d1w = (const float*)d_in[22];
    const float* d1b = (const float*)d_in[23];
    const float* d2w = (const float*)d_in[24];
    const float* d2b = (const float*)d_in[25];
    const float* d3w = (const float*)d_in[26];
    const float* d3b = (const float*)d_in[27];
    float* out = (float*)d_out;

    float* ws = (float*)d_ws;
    size_t off = 0;
    auto take = [&](size_t n) {
        float* p = ws + off;
        off += (n + 63) & ~(size_t)63;
        return p;
    };
    int* mask_i = (int*)take(2048);
    float* feat = take(2048UL * 1664);
    float* xg1f = take(2048UL * 384);
    float* xg1b = take(2048UL * 384);
    float* gru1 = take(2048UL * 256);
    float* xg2f = take(2048UL * 384);
    float* xg2b = take(2048UL * 384);
    float* gru2 = take(2048UL * 256);
    float* sc = take(4UL * 512 * 512);
    float* attn = take(2048UL * 256);
    float* fc1 = take(2048UL * 256);
    float* fc2 = take(2048UL * 256);
    unsigned short* bth = (unsigned short*)take(65536);  // 128x1024 ushort
    unsigned short* btl = (unsigned short*)take(65536);

    mask_decode_kernel<<<1, 256, 0, stream>>>(mraw, mask_i);
    prepack_w2<<<512, 256, 0, stream>>>(c2w, bth, btl);
    conv_kernel<<<2048, 256, 0, stream>>>(x, c1w, c1b, bth, btl, c2b, feat);

    // GRU layer 1 input projections (+input bias row 0)
    gemm_nn<0><<<dim3(6, 32, 1), 256, 0, stream>>>(feat, 0, g1fW, 0, g1fb, nullptr,
                                                   xg1f, 0, 2048, 384, 1664);
    gemm_nn<0><<<dim3(6, 32, 1), 256, 0, stream>>>(feat, 0, g1bW, 0, g1bb, nullptr,
                                                   xg1b, 0, 2048, 384, 1664);
    gru_kernel<<<8, 768, 0, stream>>>(xg1f, xg1b, g1fU, g1bU, g1fb + 384,
                                      g1bb + 384, s1f, s1b, mask_i, gru1);

    gemm_nn<0><<<dim3(6, 32, 1), 256, 0, stream>>>(gru1, 0, g2fW, 0, g2fb, nullptr,
                                                   xg2f, 0, 2048, 384, 256);
    gemm_nn<0><<<dim3(6, 32, 1), 256, 0, stream>>>(gru1, 0, g2bW, 0, g2bb, nullptr,
                                                   xg2b, 0, 2048, 384, 256);
    gru_kernel<<<8, 768, 0, stream>>>(xg2f, xg2b, g2fU, g2bU, g2fb + 384,
                                      g2bb + 384, s2f, s2b, mask_i, gru2);

    // attention
    scores_kernel<<<dim3(8, 8, 4), 256, 0, stream>>>(gru2, mask_i, sc);
    softmax_kernel<<<2048, 256, 0, stream>>>(sc);
    gemm_nn<0><<<dim3(4, 8, 4), 256, 0, stream>>>(sc, 512L * 512, gru2, 512L * 256,
                                                  nullptr, mask_i, attn, 512L * 256,
                                                  512, 256, 512);

    // dense head
    gemm_nn<1><<<dim3(4, 32, 1), 256, 0, stream>>>(attn, 0, d1w, 0, d1b, nullptr,
                                                   fc1, 0, 2048, 256, 256);
    gemm_nn<1><<<dim3(4, 32, 1), 256, 0, stream>>>(fc1, 0, d2w, 0, d2b, nullptr,
                                                   fc2, 0, 2048, 256, 256);
    final_kernel<<<512, 256, 0, stream>>>(fc2, d3w, d3b, out);
}

// Round 4
// 1067.418 us; speedup vs baseline: 1.2549x; 1.0869x over previous
//
#include <hip/hip_runtime.h>

#define LRELU(v) ((v) > 0.f ? (v) : 0.2f * (v))

typedef float f32x4 __attribute__((ext_vector_type(4)));
typedef __bf16 bf16x8 __attribute__((ext_vector_type(8)));
typedef unsigned short ushort8v __attribute__((ext_vector_type(8)));

__device__ __forceinline__ unsigned short f2bf(float f) {
    unsigned int u = __float_as_uint(f);
    u += 0x7fffu + ((u >> 16) & 1u);
    return (unsigned short)(u >> 16);
}
__device__ __forceinline__ float bf2f(unsigned short h) {
    return __uint_as_float(((unsigned int)h) << 16);
}
__device__ __forceinline__ float sigmoid_fast(float x) {
    float e = __builtin_amdgcn_exp2f(-x * 1.442695041f);
    return __builtin_amdgcn_rcpf(1.f + e);
}
__device__ __forceinline__ float tanh_fast(float x) {
    float e = __builtin_amdgcn_exp2f(x * 2.885390082f);  // e^(2x)
    return 1.f - 2.f * __builtin_amdgcn_rcpf(e + 1.f);
}

// ---------------------------------------------------------------------------
// mask decode: input may be bool (1B) or int32 (4B). Sniff deterministically.
// ---------------------------------------------------------------------------
__global__ void mask_decode_kernel(const unsigned int* __restrict__ mraw,
                                   int* __restrict__ mi) {
    __shared__ int is_u8;
    if (threadIdx.x == 0) {
        int u8 = 0;
        for (int i = 0; i < 512; i++) {
            if (mraw[i] > 1u) { u8 = 1; break; }
        }
        is_u8 = u8;
    }
    __syncthreads();
    if (is_u8) {
        const unsigned char* b8 = (const unsigned char*)mraw;
        for (int i = threadIdx.x; i < 2048; i += blockDim.x) mi[i] = b8[i] ? 1 : 0;
    } else {
        for (int i = threadIdx.x; i < 2048; i += blockDim.x) mi[i] = mraw[i] ? 1 : 0;
    }
}

// ---------------------------------------------------------------------------
// prepack w2 (8,128,128) -> B^T bf16 hi/lo: Bt[c][k], k = f*128+cin (1024)
// ---------------------------------------------------------------------------
__global__ __launch_bounds__(256) void prepack_w2(const float* __restrict__ w2,
                                                  unsigned short* __restrict__ bth,
                                                  unsigned short* __restrict__ btl) {
    int idx = blockIdx.x * 256 + threadIdx.x;  // 131072 total
    int c = idx >> 10, k = idx & 1023;
    float v = w2[k * 128 + c];
    unsigned short hi = f2bf(v);
    unsigned short lo = f2bf(v - bf2f(hi));
    bth[(long)c * 1024 + k] = hi;
    btl[(long)c * 1024 + k] = lo;
}

// ---------------------------------------------------------------------------
// Fused conv1(fp32)+pool1 -> LDS bf16 hi/lo -> conv2 via split-bf16 MFMA +
// fused leaky+pool2. One block (256 thr, 4 waves) per sequence.
// ---------------------------------------------------------------------------
__global__ __launch_bounds__(256) void conv_kernel(
    const float* __restrict__ x, const float* __restrict__ w1,
    const float* __restrict__ b1, const unsigned short* __restrict__ bth,
    const unsigned short* __restrict__ btl, const float* __restrict__ b2,
    float* __restrict__ feat) {
    __shared__ float xs[3][256];
    __shared__ __align__(16) unsigned short p1h[72 * 128];
    __shared__ __align__(16) unsigned short p1l[72 * 128];
    long s = blockIdx.x;
    int tid = threadIdx.x;
    const float* xp = x + s * 768;
    for (int i = tid; i < 768; i += 256) xs[i % 3][i / 3] = xp[i];
    for (int i = tid; i < 10 * 128; i += 256) {
        p1h[62 * 128 + i] = 0;
        p1l[62 * 128 + i] = 0;
    }
    __syncthreads();

    {   // conv1 + pool1, fp32, swizzled bf16 hi/lo store
        int ch = tid & 127;
        int half = tid >> 7;
        float w1r[24];
#pragma unroll
        for (int fc = 0; fc < 24; fc++) w1r[fc] = w1[fc * 128 + ch];
        float bias1 = b1[ch];
        for (int po = half; po < 62; po += 2) {
            int p0 = po * 4;
            float a0 = bias1, a1 = bias1, a2 = bias1, a3 = bias1;
#pragma unroll
            for (int c = 0; c < 3; c++) {
                float xv[11];
#pragma unroll
                for (int q = 0; q < 11; q++) xv[q] = xs[c][p0 + q];
#pragma unroll
                for (int f = 0; f < 8; f++) {
                    float w = w1r[f * 3 + c];
                    a0 = fmaf(xv[f + 0], w, a0);
                    a1 = fmaf(xv[f + 1], w, a1);
                    a2 = fmaf(xv[f + 2], w, a2);
                    a3 = fmaf(xv[f + 3], w, a3);
                }
            }
            float m01 = fmaxf(LRELU(a0), LRELU(a1));
            float m23 = fmaxf(LRELU(a2), LRELU(a3));
            float v = fmaxf(m01, m23);
            unsigned short hi = f2bf(v);
            unsigned short lo = f2bf(v - bf2f(hi));
            int cs = ch ^ ((po & 7) << 3);
            p1h[po * 128 + cs] = hi;
            p1l[po * 128 + cs] = lo;
        }
    }
    __syncthreads();

    // MFMA conv2: M=64 (55 valid), N=128, K=1024. Wave w owns N-tiles {2w,2w+1}.
    const int l = tid & 63, w = tid >> 6;
    const int r = l & 15, g = l >> 4;
    f32x4 acc[4][2];
    const f32x4 zz = {0.f, 0.f, 0.f, 0.f};
#pragma unroll
    for (int m = 0; m < 4; m++) {
        acc[m][0] = zz;
        acc[m][1] = zz;
    }
#pragma unroll 2
    for (int ks = 0; ks < 32; ks++) {
        const int f = ks >> 2;
        const int cin0 = ((ks & 3) << 5) + (g << 3);
        bf16x8 bh[2], bl[2];
#pragma unroll
        for (int n = 0; n < 2; n++) {
            const int c = ((w << 1) + n) * 16 + r;
            const long bo = (long)c * 1024 + (ks << 5) + (g << 3);
            bh[n] = __builtin_bit_cast(bf16x8, *(const ushort8v*)(bth + bo));
            bl[n] = __builtin_bit_cast(bf16x8, *(const ushort8v*)(btl + bo));
        }
        bf16x8 ah[4], al[4];
#pragma unroll
        for (int m = 0; m < 4; m++) {
            const int row = m * 16 + r + f;
            const int col = cin0 ^ ((row & 7) << 3);
            const int off = row * 128 + col;
            ah[m] = __builtin_bit_cast(bf16x8, *(const ushort8v*)(p1h + off));
            al[m] = __builtin_bit_cast(bf16x8, *(const ushort8v*)(p1l + off));
        }
#pragma unroll
        for (int m = 0; m < 4; m++) {
#pragma unroll
            for (int n = 0; n < 2; n++) {
                acc[m][n] = __builtin_amdgcn_mfma_f32_16x16x32_bf16(ah[m], bh[n], acc[m][n], 0, 0, 0);
                acc[m][n] = __builtin_amdgcn_mfma_f32_16x16x32_bf16(ah[m], bl[n], acc[m][n], 0, 0, 0);
                acc[m][n] = __builtin_amdgcn_mfma_f32_16x16x32_bf16(al[m], bh[n], acc[m][n], 0, 0, 0);
            }
        }
    }
#pragma unroll
    for (int m = 0; m < 4; m++) {
        const int j = m * 4 + g;
        if (j < 13) {
#pragma unroll
            for (int n = 0; n < 2; n++) {
                const int ch = ((w << 1) + n) * 16 + r;
                const float bias = b2[ch];
                float v0 = LRELU(acc[m][n].x + bias);
                float v1 = LRELU(acc[m][n].y + bias);
                float v2 = LRELU(acc[m][n].z + bias);
                float v3 = LRELU(acc[m][n].w + bias);
                feat[s * 1664 + j * 128 + ch] = fmaxf(fmaxf(v0, v1), fmaxf(v2, v3));
            }
        }
    }
}

// ---------------------------------------------------------------------------
// Generic batched fp32 GEMM: C = act(A @ B + bias) * rowmask
// ---------------------------------------------------------------------------
template <int ACT>
__global__ __launch_bounds__(256) void gemm_nn(
    const float* __restrict__ A, long sA, const float* __restrict__ B, long sB,
    const float* __restrict__ bias, const int* __restrict__ qmask,
    float* __restrict__ C, long sC, int M, int N, int K) {
    int bz = blockIdx.z;
    A += (long)bz * sA;
    B += (long)bz * sB;
    C += (long)bz * sC;
    __shared__ __align__(16) float As[16][68];
    __shared__ __align__(16) float Bs[16][68];
    int tid = threadIdx.x;
    int tm = tid >> 4, tn = tid & 15;
    int m0 = blockIdx.y * 64, n0 = blockIdx.x * 64;
    int la_m = tid & 63, la_k = (tid >> 6) * 4;
    int lb_k = tid >> 4, lb_n = (tid & 15) * 4;
    float acc[4][4] = {};
    for (int k0 = 0; k0 < K; k0 += 16) {
        float4 av = *(const float4*)&A[(long)(m0 + la_m) * K + k0 + la_k];
        float4 bv = *(const float4*)&B[(long)(k0 + lb_k) * N + n0 + lb_n];
        As[la_k + 0][la_m] = av.x;
        As[la_k + 1][la_m] = av.y;
        As[la_k + 2][la_m] = av.z;
        As[la_k + 3][la_m] = av.w;
        *(float4*)&Bs[lb_k][lb_n] = bv;
        __syncthreads();
#pragma unroll
        for (int k = 0; k < 16; k++) {
            float4 a4 = *(const float4*)&As[k][tm * 4];
            float4 b4 = *(const float4*)&Bs[k][tn * 4];
            float aa[4] = {a4.x, a4.y, a4.z, a4.w};
            float bb[4] = {b4.x, b4.y, b4.z, b4.w};
#pragma unroll
            for (int i = 0; i < 4; i++)
#pragma unroll
                for (int j = 0; j < 4; j++) acc[i][j] = fmaf(aa[i], bb[j], acc[i][j]);
        }
        __syncthreads();
    }
#pragma unroll
    for (int i = 0; i < 4; i++) {
        int row = m0 + tm * 4 + i;
        float msc = qmask ? (float)qmask[(long)bz * M + row] : 1.f;
#pragma unroll
        for (int j = 0; j < 4; j++) {
            int col = n0 + tn * 4 + j;
            float v = acc[i][j] + (bias ? bias[col] : 0.f);
            if (ACT == 1) v = LRELU(v);
            C[(long)row * N + col] = v * msc;
        }
    }
}

// ---------------------------------------------------------------------------
// scores = h @ h^T with key-mask (-1e9), batched over 4.
// ---------------------------------------------------------------------------
__global__ __launch_bounds__(256) void scores_kernel(
    const float* __restrict__ h, const int* __restrict__ mask,
    float* __restrict__ S) {
    int bz = blockIdx.z;
    const float* A = h + (long)bz * 512 * 256;
    float* C = S + (long)bz * 512 * 512;
    __shared__ __align__(16) float As[16][68];
    __shared__ __align__(16) float Bs[16][68];
    int tid = threadIdx.x;
    int tm = tid >> 4, tn = tid & 15;
    int m0 = blockIdx.y * 64, n0 = blockIdx.x * 64;
    int lr = tid & 63, lk = (tid >> 6) * 4;
    float acc[4][4] = {};
    for (int k0 = 0; k0 < 256; k0 += 16) {
        float4 av = *(const float4*)&A[(long)(m0 + lr) * 256 + k0 + lk];
        float4 bv = *(const float4*)&A[(long)(n0 + lr) * 256 + k0 + lk];
        As[lk + 0][lr] = av.x;
        As[lk + 1][lr] = av.y;
        As[lk + 2][lr] = av.z;
        As[lk + 3][lr] = av.w;
        Bs[lk + 0][lr] = bv.x;
        Bs[lk + 1][lr] = bv.y;
        Bs[lk + 2][lr] = bv.z;
        Bs[lk + 3][lr] = bv.w;
        __syncthreads();
#pragma unroll
        for (int k = 0; k < 16; k++) {
            float4 a4 = *(const float4*)&As[k][tm * 4];
            float4 b4 = *(const float4*)&Bs[k][tn * 4];
            float aa[4] = {a4.x, a4.y, a4.z, a4.w};
            float bb[4] = {b4.x, b4.y, b4.z, b4.w};
#pragma unroll
            for (int i = 0; i < 4; i++)
#pragma unroll
                for (int j = 0; j < 4; j++) acc[i][j] = fmaf(aa[i], bb[j], acc[i][j]);
        }
        __syncthreads();
    }
#pragma unroll
    for (int i = 0; i < 4; i++) {
        int t = m0 + tm * 4 + i;
#pragma unroll
        for (int j = 0; j < 4; j++) {
            int ss = n0 + tn * 4 + j;
            C[(long)t * 512 + ss] = mask[bz * 512 + ss] ? acc[i][j] : -1e9f;
        }
    }
}

// row softmax over 512, block per row
__global__ __launch_bounds__(256) void softmax_kernel(float* __restrict__ S) {
    long row = blockIdx.x;
    float* p = S + row * 512;
    int tid = threadIdx.x;
    __shared__ float red[8];
    float v0 = p[tid], v1 = p[tid + 256];
    float mx = fmaxf(v0, v1);
#pragma unroll
    for (int off = 32; off; off >>= 1) mx = fmaxf(mx, __shfl_down(mx, off));
    if ((tid & 63) == 0) red[tid >> 6] = mx;
    __syncthreads();
    mx = fmaxf(fmaxf(red[0], red[1]), fmaxf(red[2], red[3]));
    float e0 = expf(v0 - mx), e1 = expf(v1 - mx);
    float sm = e0 + e1;
#pragma unroll
    for (int off = 32; off; off >>= 1) sm += __shfl_down(sm, off);
    if ((tid & 63) == 0) red[4 + (tid >> 6)] = sm;
    __syncthreads();
    float inv = 1.f / (red[4] + red[5] + red[6] + red[7]);
    p[tid] = e0 * inv;
    p[tid + 256] = e1 * inv;
}

// ---------------------------------------------------------------------------
// GRU scan v3. 8 blocks = (batch) x (dir), 768 threads = 12 waves.
// tid -> gate = tid>>8 (z,r,h), cp = (tid&255)>>1, half = tid&1 (K-split).
// xg staged in 16-step LDS chunks via async global_load_lds (double-buffered,
// issued one chunk ahead). Step loop uses RAW s_barrier + lgkmcnt(0) only --
// global loads/stores stay in flight across steps; vmcnt(0) only at chunk
// boundaries (where the waited ops are 16 steps old = free). U pinned in
// VGPRs via asm to prevent rematerialized per-step global loads.
// ---------------------------------------------------------------------------
__global__ __launch_bounds__(768) void gru_kernel(
    const float* __restrict__ xgf, const float* __restrict__ xgb,
    const float* __restrict__ Uf, const float* __restrict__ Ub,
    const float* __restrict__ brf, const float* __restrict__ brb,
    const float* __restrict__ h0f, const float* __restrict__ h0b,
    const int* __restrict__ mask, float* __restrict__ out) {
    int b = blockIdx.x & 3;
    int dir = blockIdx.x >> 2;
    const float* __restrict__ xg = dir ? xgb : xgf;
    const float* __restrict__ U = dir ? Ub : Uf;
    const float* __restrict__ br = dir ? brb : brf;
    const float* __restrict__ h0 = dir ? h0b : h0f;
    const int tid = threadIdx.x;
    const int gate = tid >> 8;
    const int cp = (tid & 255) >> 1;
    const int half = tid & 1;
    const int ucol = gate * 128 + cp;

    __shared__ __align__(16) float xs[2][16 * 384];  // 2 x 24 KB chunks
    __shared__ __align__(16) float hsh[128];
    __shared__ float zs[128], rs[128], gxv[128], grv[128];
    __shared__ unsigned long long mwords[8];

    // stage chunk c (16 steps x 384 floats) into xs[bufi], async to LDS
    auto stage = [&](int c, int bufi) {
#pragma unroll
        for (int i = 0; i < 2; i++) {
            int g = i * 768 + tid;       // 16B-group index, 0..1535
            int j = g / 96;              // step-in-chunk 0..15
            int col = (g - j * 96) * 4;  // 0..383
            int ts = c * 16 + j;
            int t = dir ? (511 - ts) : ts;
            const float* src = xg + ((long)(b * 512 + t)) * 384 + col;
            __builtin_amdgcn_global_load_lds(
                (const __attribute__((address_space(1))) void*)src,
                (__attribute__((address_space(3))) void*)&xs[bufi][g * 4], 16, 0, 0);
        }
    };

    stage(0, 0);

    // U column in registers, pinned
    f32x4 u4[16];
#pragma unroll
    for (int k = 0; k < 16; k++) {
        int kb = half * 64 + k * 4;
        u4[k].x = U[(kb + 0) * 384 + ucol];
        u4[k].y = U[(kb + 1) * 384 + ucol];
        u4[k].z = U[(kb + 2) * 384 + ucol];
        u4[k].w = U[(kb + 3) * 384 + ucol];
    }
#pragma unroll
    for (int k = 0; k < 16; k++) asm volatile("" : "+v"(u4[k]));
    float brv = br[ucol];

    float hreg = 0.f;
    if (tid < 128) {
        hreg = h0[b * 128 + tid];
        hsh[tid] = hreg;
    }
    if (tid < 64) {  // wave 0 builds the step-order mask bitmap
#pragma unroll
        for (int w = 0; w < 8; w++) {
            int idx = w * 64 + tid;
            int t = dir ? (511 - idx) : idx;
            unsigned long long bm = __ballot(mask[b * 512 + t] != 0);
            if (tid == 0) mwords[w] = bm;
        }
    }
    asm volatile("s_waitcnt lgkmcnt(0)" ::: "memory");
    __builtin_amdgcn_s_barrier();

    for (int c = 0; c < 32; c++) {
        // chunk-c loads (issued one chunk ago, or just above for c=0) + old
        // stores: wait then issue next chunk async.
        asm volatile("s_waitcnt vmcnt(0)" ::: "memory");
        if (c < 31) stage(c + 1, (c + 1) & 1);
        __builtin_amdgcn_s_barrier();  // all waves' chunk-c data now visible
        __builtin_amdgcn_sched_barrier(0);
        const float* xb = xs[c & 1];
        unsigned mwbits = (unsigned)((mwords[c >> 2] >> ((c & 3) * 16)) & 0xffffull);
#pragma unroll 1
        for (int jj = 0; jj < 16; jj++) {
            int step = c * 16 + jj;
            int t = dir ? (511 - step) : step;
            long obase = ((long)(b * 512 + t)) * 256 + dir * 128;
            int mt = (mwbits >> jj) & 1;
            if (mt) {
                float xtv = xb[jj * 384 + ucol];
                const float* hh = hsh + half * 64;
                float a0 = 0.f, a1 = 0.f, a2 = 0.f, a3 = 0.f;
#pragma unroll
                for (int k = 0; k < 16; k++) {
                    float4 hv = *(const float4*)&hh[k * 4];
                    a0 = fmaf(hv.x, u4[k].x, a0);
                    a1 = fmaf(hv.y, u4[k].y, a1);
                    a2 = fmaf(hv.z, u4[k].z, a2);
                    a3 = fmaf(hv.w, u4[k].w, a3);
                }
                float rg = (a0 + a1) + (a2 + a3);
                rg += __shfl_xor(rg, 1);
                rg += brv;
                if (half == 0) {
                    if (gate == 0) zs[cp] = sigmoid_fast(xtv + rg);
                    else if (gate == 1) rs[cp] = sigmoid_fast(xtv + rg);
                    else { gxv[cp] = xtv; grv[cp] = rg; }
                }
                asm volatile("s_waitcnt lgkmcnt(0)" ::: "memory");
                __builtin_amdgcn_s_barrier();
                if (tid < 128) {
                    float z = zs[tid], r_ = rs[tid];
                    float hhv = tanh_fast(fmaf(r_, grv[tid], gxv[tid]));
                    float hn = fmaf(z, hreg - hhv, hhv);
                    hreg = hn;
                    hsh[tid] = hn;
                    out[obase + tid] = hn;  // in-flight store, drained at boundary
                }
                asm volatile("s_waitcnt lgkmcnt(0)" ::: "memory");
                __builtin_amdgcn_s_barrier();
            } else {
                if (tid < 128) out[obase + tid] = hreg;
            }
        }
    }
}

// final dense 256 -> 1, one wave per row
__global__ __launch_bounds__(256) void final_kernel(
    const float* __restrict__ fc2, const float* __restrict__ w,
    const float* __restrict__ b, float* __restrict__ out) {
    int row = blockIdx.x * 4 + (threadIdx.x >> 6);
    int lane = threadIdx.x & 63;
    const float* a = fc2 + (long)row * 256;
    float acc = 0.f;
#pragma unroll
    for (int i = 0; i < 4; i++) acc = fmaf(a[lane + i * 64], w[lane + i * 64], acc);
#pragma unroll
    for (int off = 32; off; off >>= 1) acc += __shfl_down(acc, off);
    if (lane == 0) out[row] = acc + b[0];
}

// ---------------------------------------------------------------------------
extern "C" void kernel_launch(void* const* d_in, const int* in_sizes, int n_in,
                              void* d_out, int out_size, void* d_ws,
                              size_t ws_size, hipStream_t stream) {
    const float* x = (const float*)d_in[0];
    const unsigned int* mraw = (const unsigned int*)d_in[1];
    const float* s1f = (const float*)d_in[2];
    const float* s1b = (const float*)d_in[3];
    const float* s2f = (const float*)d_in[4];
    const float* s2b = (const float*)d_in[5];
    const float* c1w = (const float*)d_in[6];
    const float* c1b = (const float*)d_in[7];
    const float* c2w = (const float*)d_in[8];
    const float* c2b = (const float*)d_in[9];
    const float* g1fW = (const float*)d_in[10];
    const float* g1fU = (const float*)d_in[11];
    const float* g1fb = (const float*)d_in[12];
    const float* g1bW = (const float*)d_in[13];
    const float* g1bU = (const float*)d_in[14];
    const float* g1bb = (const float*)d_in[15];
    const float* g2fW = (const float*)d_in[16];
    const float* g2fU = (const float*)d_in[17];
    const float* g2fb = (const float*)d_in[18];
    const float* g2bW = (const float*)d_in[19];
    const float* g2bU = (const float*)d_in[20];
    const float* g2bb = (const float*)d_in[21];
    const float* d1w = (const float*)d_in[22];
    const float* d1b = (const float*)d_in[23];
    const float* d2w = (const float*)d_in[24];
    const float* d2b = (const float*)d_in[25];
    const float* d3w = (const float*)d_in[26];
    const float* d3b = (const float*)d_in[27];
    float* out = (float*)d_out;

    float* ws = (float*)d_ws;
    size_t off = 0;
    auto take = [&](size_t n) {
        float* p = ws + off;
        off += (n + 63) & ~(size_t)63;
        return p;
    };
    int* mask_i = (int*)take(2048);
    float* feat = take(2048UL * 1664);
    float* xg1f = take(2048UL * 384);
    float* xg1b = take(2048UL * 384);
    float* gru1 = take(2048UL * 256);
    float* xg2f = take(2048UL * 384);
    float* xg2b = take(2048UL * 384);
    float* gru2 = take(2048UL * 256);
    float* sc = take(4UL * 512 * 512);
    float* attn = take(2048UL * 256);
    float* fc1 = take(2048UL * 256);
    float* fc2 = take(2048UL * 256);
    unsigned short* bth = (unsigned short*)take(65536);  // 128x1024 ushort
    unsigned short* btl = (unsigned short*)take(65536);

    mask_decode_kernel<<<1, 256, 0, stream>>>(mraw, mask_i);
    prepack_w2<<<512, 256, 0, stream>>>(c2w, bth, btl);
    conv_kernel<<<2048, 256, 0, stream>>>(x, c1w, c1b, bth, btl, c2b, feat);

    // GRU layer 1 input projections (+input bias row 0)
    gemm_nn<0><<<dim3(6, 32, 1), 256, 0, stream>>>(feat, 0, g1fW, 0, g1fb, nullptr,
                                                   xg1f, 0, 2048, 384, 1664);
    gemm_nn<0><<<dim3(6, 32, 1), 256, 0, stream>>>(feat, 0, g1bW, 0, g1bb, nullptr,
                                                   xg1b, 0, 2048, 384, 1664);
    gru_kernel<<<8, 768, 0, stream>>>(xg1f, xg1b, g1fU, g1bU, g1fb + 384,
                                      g1bb + 384, s1f, s1b, mask_i, gru1);

    gemm_nn<0><<<dim3(6, 32, 1), 256, 0, stream>>>(gru1, 0, g2fW, 0, g2fb, nullptr,
                                                   xg2f, 0, 2048, 384, 256);
    gemm_nn<0><<<dim3(6, 32, 1), 256, 0, stream>>>(gru1, 0, g2bW, 0, g2bb, nullptr,
                                                   xg2b, 0, 2048, 384, 256);
    gru_kernel<<<8, 768, 0, stream>>>(xg2f, xg2b, g2fU, g2bU, g2fb + 384,
                                      g2bb + 384, s2f, s2b, mask_i, gru2);

    // attention
    scores_kernel<<<dim3(8, 8, 4), 256, 0, stream>>>(gru2, mask_i, sc);
    softmax_kernel<<<2048, 256, 0, stream>>>(sc);
    gemm_nn<0><<<dim3(4, 8, 4), 256, 0, stream>>>(sc, 512L * 512, gru2, 512L * 256,
                                                  nullptr, mask_i, attn, 512L * 256,
                                                  512, 256, 512);

    // dense head
    gemm_nn<1><<<dim3(4, 32, 1), 256, 0, stream>>>(attn, 0, d1w, 0, d1b, nullptr,
                                                   fc1, 0, 2048, 256, 256);
    gemm_nn<1><<<dim3(4, 32, 1), 256, 0, stream>>>(fc1, 0, d2w, 0, d2b, nullptr,
                                                   fc2, 0, 2048, 256, 256);
    final_kernel<<<512, 256, 0, stream>>>(fc2, d3w, d3b, out);
}

// Round 5
// 894.570 us; speedup vs baseline: 1.4974x; 1.1932x over previous
//
#include <hip/hip_runtime.h>

#define LRELU(v) ((v) > 0.f ? (v) : 0.2f * (v))

typedef float f32x4 __attribute__((ext_vector_type(4)));
typedef __bf16 bf16x8 __attribute__((ext_vector_type(8)));
typedef unsigned short ushort8v __attribute__((ext_vector_type(8)));

__device__ __forceinline__ unsigned short f2bf(float f) {
    unsigned int u = __float_as_uint(f);
    u += 0x7fffu + ((u >> 16) & 1u);
    return (unsigned short)(u >> 16);
}
__device__ __forceinline__ float bf2f(unsigned short h) {
    return __uint_as_float(((unsigned int)h) << 16);
}
__device__ __forceinline__ float sigmoid_fast(float x) {
    float e = __builtin_amdgcn_exp2f(-x * 1.442695041f);
    return __builtin_amdgcn_rcpf(1.f + e);
}
__device__ __forceinline__ float tanh_fast(float x) {
    float e = __builtin_amdgcn_exp2f(x * 2.885390082f);  // e^(2x)
    return 1.f - 2.f * __builtin_amdgcn_rcpf(e + 1.f);
}

// ---------------------------------------------------------------------------
// mask decode: input may be bool (1B) or int32 (4B). Sniff deterministically.
// ---------------------------------------------------------------------------
__global__ void mask_decode_kernel(const unsigned int* __restrict__ mraw,
                                   int* __restrict__ mi) {
    __shared__ int is_u8;
    if (threadIdx.x == 0) {
        int u8 = 0;
        for (int i = 0; i < 512; i++) {
            if (mraw[i] > 1u) { u8 = 1; break; }
        }
        is_u8 = u8;
    }
    __syncthreads();
    if (is_u8) {
        const unsigned char* b8 = (const unsigned char*)mraw;
        for (int i = threadIdx.x; i < 2048; i += blockDim.x) mi[i] = b8[i] ? 1 : 0;
    } else {
        for (int i = threadIdx.x; i < 2048; i += blockDim.x) mi[i] = mraw[i] ? 1 : 0;
    }
}

// ---------------------------------------------------------------------------
// prepack w2 (8,128,128) -> B^T bf16 hi/lo: Bt[c][k], k = f*128+cin (1024)
// ---------------------------------------------------------------------------
__global__ __launch_bounds__(256) void prepack_w2(const float* __restrict__ w2,
                                                  unsigned short* __restrict__ bth,
                                                  unsigned short* __restrict__ btl) {
    int idx = blockIdx.x * 256 + threadIdx.x;  // 131072 total
    int c = idx >> 10, k = idx & 1023;
    float v = w2[k * 128 + c];
    unsigned short hi = f2bf(v);
    unsigned short lo = f2bf(v - bf2f(hi));
    bth[(long)c * 1024 + k] = hi;
    btl[(long)c * 1024 + k] = lo;
}

// ---------------------------------------------------------------------------
// generic prepack: W (K x N) fp32 -> Wt hi/lo (N x K) bf16
// ---------------------------------------------------------------------------
__global__ __launch_bounds__(256) void prepack_wt(const float* __restrict__ W,
                                                  unsigned short* __restrict__ h,
                                                  unsigned short* __restrict__ l,
                                                  int K, int N) {
    long idx = (long)blockIdx.x * 256 + threadIdx.x;
    if (idx >= (long)K * N) return;
    int n = (int)(idx / K), k = (int)(idx % K);
    float v = W[(long)k * N + n];
    unsigned short hi = f2bf(v);
    unsigned short lo = f2bf(v - bf2f(hi));
    h[idx] = hi;
    l[idx] = lo;
}

// ---------------------------------------------------------------------------
// Fused conv1(fp32)+pool1 -> LDS bf16 hi/lo -> conv2 via split-bf16 MFMA +
// fused leaky+pool2. One block (256 thr, 4 waves) per sequence.
// ---------------------------------------------------------------------------
__global__ __launch_bounds__(256) void conv_kernel(
    const float* __restrict__ x, const float* __restrict__ w1,
    const float* __restrict__ b1, const unsigned short* __restrict__ bth,
    const unsigned short* __restrict__ btl, const float* __restrict__ b2,
    float* __restrict__ feat) {
    __shared__ float xs[3][256];
    __shared__ __align__(16) unsigned short p1h[72 * 128];
    __shared__ __align__(16) unsigned short p1l[72 * 128];
    long s = blockIdx.x;
    int tid = threadIdx.x;
    const float* xp = x + s * 768;
    for (int i = tid; i < 768; i += 256) xs[i % 3][i / 3] = xp[i];
    for (int i = tid; i < 10 * 128; i += 256) {
        p1h[62 * 128 + i] = 0;
        p1l[62 * 128 + i] = 0;
    }
    __syncthreads();

    {   // conv1 + pool1, fp32, swizzled bf16 hi/lo store
        int ch = tid & 127;
        int half = tid >> 7;
        float w1r[24];
#pragma unroll
        for (int fc = 0; fc < 24; fc++) w1r[fc] = w1[fc * 128 + ch];
        float bias1 = b1[ch];
        for (int po = half; po < 62; po += 2) {
            int p0 = po * 4;
            float a0 = bias1, a1 = bias1, a2 = bias1, a3 = bias1;
#pragma unroll
            for (int c = 0; c < 3; c++) {
                float xv[11];
#pragma unroll
                for (int q = 0; q < 11; q++) xv[q] = xs[c][p0 + q];
#pragma unroll
                for (int f = 0; f < 8; f++) {
                    float w = w1r[f * 3 + c];
                    a0 = fmaf(xv[f + 0], w, a0);
                    a1 = fmaf(xv[f + 1], w, a1);
                    a2 = fmaf(xv[f + 2], w, a2);
                    a3 = fmaf(xv[f + 3], w, a3);
                }
            }
            float m01 = fmaxf(LRELU(a0), LRELU(a1));
            float m23 = fmaxf(LRELU(a2), LRELU(a3));
            float v = fmaxf(m01, m23);
            unsigned short hi = f2bf(v);
            unsigned short lo = f2bf(v - bf2f(hi));
            int cs = ch ^ ((po & 7) << 3);
            p1h[po * 128 + cs] = hi;
            p1l[po * 128 + cs] = lo;
        }
    }
    __syncthreads();

    const int l = tid & 63, w = tid >> 6;
    const int r = l & 15, g = l >> 4;
    f32x4 acc[4][2];
    const f32x4 zz = {0.f, 0.f, 0.f, 0.f};
#pragma unroll
    for (int m = 0; m < 4; m++) {
        acc[m][0] = zz;
        acc[m][1] = zz;
    }
#pragma unroll 2
    for (int ks = 0; ks < 32; ks++) {
        const int f = ks >> 2;
        const int cin0 = ((ks & 3) << 5) + (g << 3);
        bf16x8 bh[2], bl[2];
#pragma unroll
        for (int n = 0; n < 2; n++) {
            const int c = ((w << 1) + n) * 16 + r;
            const long bo = (long)c * 1024 + (ks << 5) + (g << 3);
            bh[n] = __builtin_bit_cast(bf16x8, *(const ushort8v*)(bth + bo));
            bl[n] = __builtin_bit_cast(bf16x8, *(const ushort8v*)(btl + bo));
        }
        bf16x8 ah[4], al[4];
#pragma unroll
        for (int m = 0; m < 4; m++) {
            const int row = m * 16 + r + f;
            const int col = cin0 ^ ((row & 7) << 3);
            const int off = row * 128 + col;
            ah[m] = __builtin_bit_cast(bf16x8, *(const ushort8v*)(p1h + off));
            al[m] = __builtin_bit_cast(bf16x8, *(const ushort8v*)(p1l + off));
        }
#pragma unroll
        for (int m = 0; m < 4; m++) {
#pragma unroll
            for (int n = 0; n < 2; n++) {
                acc[m][n] = __builtin_amdgcn_mfma_f32_16x16x32_bf16(ah[m], bh[n], acc[m][n], 0, 0, 0);
                acc[m][n] = __builtin_amdgcn_mfma_f32_16x16x32_bf16(ah[m], bl[n], acc[m][n], 0, 0, 0);
                acc[m][n] = __builtin_amdgcn_mfma_f32_16x16x32_bf16(al[m], bh[n], acc[m][n], 0, 0, 0);
            }
        }
    }
#pragma unroll
    for (int m = 0; m < 4; m++) {
        const int j = m * 4 + g;
        if (j < 13) {
#pragma unroll
            for (int n = 0; n < 2; n++) {
                const int ch = ((w << 1) + n) * 16 + r;
                const float bias = b2[ch];
                float v0 = LRELU(acc[m][n].x + bias);
                float v1 = LRELU(acc[m][n].y + bias);
                float v2 = LRELU(acc[m][n].z + bias);
                float v3 = LRELU(acc[m][n].w + bias);
                feat[s * 1664 + j * 128 + ch] = fmaxf(fmaxf(v0, v1), fmaxf(v2, v3));
            }
        }
    }
}

// ---------------------------------------------------------------------------
// MFMA GEMM: C(M,N) = act(A(M,K,fp32) @ W + bias) using prepacked Wt hi/lo
// (N x K bf16). 64x64 tile, 256 thr / 4 waves, wave w -> 16-col strip.
// A staged per 32-K chunk into LDS as bf16 hi/lo with granule XOR swizzle.
// ---------------------------------------------------------------------------
template <int ACT>
__global__ __launch_bounds__(256) void gemm_bf16(
    const float* __restrict__ A, const unsigned short* __restrict__ Wth,
    const unsigned short* __restrict__ Wtl, const float* __restrict__ bias,
    float* __restrict__ C, int M, int N, int K) {
    __shared__ __align__(16) unsigned short Ah[64 * 40];
    __shared__ __align__(16) unsigned short Al[64 * 40];
    const int tid = threadIdx.x;
    const int w = tid >> 6, l = tid & 63, r = l & 15, g = l >> 4;
    const int m0 = blockIdx.y * 64, n0 = blockIdx.x * 64;
    const int col = n0 + w * 16 + r;
    const int srow = tid >> 2, sgq = tid & 3;
    f32x4 acc[4];
    const f32x4 zz = {0.f, 0.f, 0.f, 0.f};
#pragma unroll
    for (int m = 0; m < 4; m++) acc[m] = zz;

    const float* ap0 = A + (long)(m0 + srow) * K + sgq * 8;
    const long bbase = (long)col * K + g * 8;
    float4 v0 = *(const float4*)ap0;
    float4 v1 = *(const float4*)(ap0 + 4);
    ushort8v bhc = *(const ushort8v*)(Wth + bbase);
    ushort8v blc = *(const ushort8v*)(Wtl + bbase);

    for (int k0 = 0; k0 < K; k0 += 32) {
        // prefetch next chunk's globals (overlap with LDS + MFMA below)
        float4 nv0, nv1;
        ushort8v nbh, nbl;
        if (k0 + 32 < K) {
            nv0 = *(const float4*)(ap0 + k0 + 32);
            nv1 = *(const float4*)(ap0 + k0 + 36);
            nbh = *(const ushort8v*)(Wth + bbase + k0 + 32);
            nbl = *(const ushort8v*)(Wtl + bbase + k0 + 32);
        }
        float vv[8] = {v0.x, v0.y, v0.z, v0.w, v1.x, v1.y, v1.z, v1.w};
        ushort8v hh, ll;
#pragma unroll
        for (int q = 0; q < 8; q++) {
            unsigned short h16 = f2bf(vv[q]);
            hh[q] = h16;
            ll[q] = f2bf(vv[q] - bf2f(h16));
        }
        const int slot = sgq ^ (srow & 3);
        __syncthreads();
        *(ushort8v*)&Ah[srow * 40 + slot * 8] = hh;
        *(ushort8v*)&Al[srow * 40 + slot * 8] = ll;
        __syncthreads();
        bf16x8 bh = __builtin_bit_cast(bf16x8, bhc);
        bf16x8 bl = __builtin_bit_cast(bf16x8, blc);
#pragma unroll
        for (int m = 0; m < 4; m++) {
            const int arow = m * 16 + r;
            const int aoff = arow * 40 + ((g ^ (arow & 3)) << 3);
            bf16x8 ah = __builtin_bit_cast(bf16x8, *(const ushort8v*)(Ah + aoff));
            bf16x8 al = __builtin_bit_cast(bf16x8, *(const ushort8v*)(Al + aoff));
            acc[m] = __builtin_amdgcn_mfma_f32_16x16x32_bf16(ah, bh, acc[m], 0, 0, 0);
            acc[m] = __builtin_amdgcn_mfma_f32_16x16x32_bf16(ah, bl, acc[m], 0, 0, 0);
            acc[m] = __builtin_amdgcn_mfma_f32_16x16x32_bf16(al, bh, acc[m], 0, 0, 0);
        }
        v0 = nv0; v1 = nv1; bhc = nbh; blc = nbl;
    }
    const float bv = bias ? bias[col] : 0.f;
#pragma unroll
    for (int m = 0; m < 4; m++) {
#pragma unroll
        for (int q = 0; q < 4; q++) {
            const int row = m0 + m * 16 + g * 4 + q;
            float v = acc[m][q] + bv;
            if (ACT == 1) v = LRELU(v);
            C[(long)row * N + col] = v;
        }
    }
}

// ---------------------------------------------------------------------------
// Generic batched fp32 GEMM: C = act(A @ B + bias) * rowmask
// ---------------------------------------------------------------------------
template <int ACT>
__global__ __launch_bounds__(256) void gemm_nn(
    const float* __restrict__ A, long sA, const float* __restrict__ B, long sB,
    const float* __restrict__ bias, const int* __restrict__ qmask,
    float* __restrict__ C, long sC, int M, int N, int K) {
    int bz = blockIdx.z;
    A += (long)bz * sA;
    B += (long)bz * sB;
    C += (long)bz * sC;
    __shared__ __align__(16) float As[16][68];
    __shared__ __align__(16) float Bs[16][68];
    int tid = threadIdx.x;
    int tm = tid >> 4, tn = tid & 15;
    int m0 = blockIdx.y * 64, n0 = blockIdx.x * 64;
    int la_m = tid & 63, la_k = (tid >> 6) * 4;
    int lb_k = tid >> 4, lb_n = (tid & 15) * 4;
    float acc[4][4] = {};
    for (int k0 = 0; k0 < K; k0 += 16) {
        float4 av = *(const float4*)&A[(long)(m0 + la_m) * K + k0 + la_k];
        float4 bv = *(const float4*)&B[(long)(k0 + lb_k) * N + n0 + lb_n];
        As[la_k + 0][la_m] = av.x;
        As[la_k + 1][la_m] = av.y;
        As[la_k + 2][la_m] = av.z;
        As[la_k + 3][la_m] = av.w;
        *(float4*)&Bs[lb_k][lb_n] = bv;
        __syncthreads();
#pragma unroll
        for (int k = 0; k < 16; k++) {
            float4 a4 = *(const float4*)&As[k][tm * 4];
            float4 b4 = *(const float4*)&Bs[k][tn * 4];
            float aa[4] = {a4.x, a4.y, a4.z, a4.w};
            float bb[4] = {b4.x, b4.y, b4.z, b4.w};
#pragma unroll
            for (int i = 0; i < 4; i++)
#pragma unroll
                for (int j = 0; j < 4; j++) acc[i][j] = fmaf(aa[i], bb[j], acc[i][j]);
        }
        __syncthreads();
    }
#pragma unroll
    for (int i = 0; i < 4; i++) {
        int row = m0 + tm * 4 + i;
        float msc = qmask ? (float)qmask[(long)bz * M + row] : 1.f;
#pragma unroll
        for (int j = 0; j < 4; j++) {
            int col = n0 + tn * 4 + j;
            float v = acc[i][j] + (bias ? bias[col] : 0.f);
            if (ACT == 1) v = LRELU(v);
            C[(long)row * N + col] = v * msc;
        }
    }
}

// ---------------------------------------------------------------------------
// scores = h @ h^T with key-mask (-1e9), batched over 4.
// ---------------------------------------------------------------------------
__global__ __launch_bounds__(256) void scores_kernel(
    const float* __restrict__ h, const int* __restrict__ mask,
    float* __restrict__ S) {
    int bz = blockIdx.z;
    const float* A = h + (long)bz * 512 * 256;
    float* C = S + (long)bz * 512 * 512;
    __shared__ __align__(16) float As[16][68];
    __shared__ __align__(16) float Bs[16][68];
    int tid = threadIdx.x;
    int tm = tid >> 4, tn = tid & 15;
    int m0 = blockIdx.y * 64, n0 = blockIdx.x * 64;
    int lr = tid & 63, lk = (tid >> 6) * 4;
    float acc[4][4] = {};
    for (int k0 = 0; k0 < 256; k0 += 16) {
        float4 av = *(const float4*)&A[(long)(m0 + lr) * 256 + k0 + lk];
        float4 bv = *(const float4*)&A[(long)(n0 + lr) * 256 + k0 + lk];
        As[lk + 0][lr] = av.x;
        As[lk + 1][lr] = av.y;
        As[lk + 2][lr] = av.z;
        As[lk + 3][lr] = av.w;
        Bs[lk + 0][lr] = bv.x;
        Bs[lk + 1][lr] = bv.y;
        Bs[lk + 2][lr] = bv.z;
        Bs[lk + 3][lr] = bv.w;
        __syncthreads();
#pragma unroll
        for (int k = 0; k < 16; k++) {
            float4 a4 = *(const float4*)&As[k][tm * 4];
            float4 b4 = *(const float4*)&Bs[k][tn * 4];
            float aa[4] = {a4.x, a4.y, a4.z, a4.w};
            float bb[4] = {b4.x, b4.y, b4.z, b4.w};
#pragma unroll
            for (int i = 0; i < 4; i++)
#pragma unroll
                for (int j = 0; j < 4; j++) acc[i][j] = fmaf(aa[i], bb[j], acc[i][j]);
        }
        __syncthreads();
    }
#pragma unroll
    for (int i = 0; i < 4; i++) {
        int t = m0 + tm * 4 + i;
#pragma unroll
        for (int j = 0; j < 4; j++) {
            int ss = n0 + tn * 4 + j;
            C[(long)t * 512 + ss] = mask[bz * 512 + ss] ? acc[i][j] : -1e9f;
        }
    }
}

// row softmax over 512, block per row
__global__ __launch_bounds__(256) void softmax_kernel(float* __restrict__ S) {
    long row = blockIdx.x;
    float* p = S + row * 512;
    int tid = threadIdx.x;
    __shared__ float red[8];
    float v0 = p[tid], v1 = p[tid + 256];
    float mx = fmaxf(v0, v1);
#pragma unroll
    for (int off = 32; off; off >>= 1) mx = fmaxf(mx, __shfl_down(mx, off));
    if ((tid & 63) == 0) red[tid >> 6] = mx;
    __syncthreads();
    mx = fmaxf(fmaxf(red[0], red[1]), fmaxf(red[2], red[3]));
    float e0 = expf(v0 - mx), e1 = expf(v1 - mx);
    float sm = e0 + e1;
#pragma unroll
    for (int off = 32; off; off >>= 1) sm += __shfl_down(sm, off);
    if ((tid & 63) == 0) red[4 + (tid >> 6)] = sm;
    __syncthreads();
    float inv = 1.f / (red[4] + red[5] + red[6] + red[7]);
    p[tid] = e0 * inv;
    p[tid + 256] = e1 * inv;
}

// ---------------------------------------------------------------------------
// GRU scan v4. 8 blocks = (batch)x(dir), 384 threads = 6 waves.
// Thread t = column c in [0,384): full-K dot, u[128] pinned in VGPRs
// (launch_bounds(384,2) -> 256 VGPR cap so the pin holds). h broadcast
// reads are WAVE-UNIFORM (all lanes read the same hsh quad -> LDS
// broadcast). Raw s_barrier + lgkmcnt in step loop; xg staged in 16-step
// async chunks; vmcnt(0) only at chunk boundaries.
// ---------------------------------------------------------------------------
__global__ __launch_bounds__(384, 2) void gru_kernel(
    const float* __restrict__ xgf, const float* __restrict__ xgb,
    const float* __restrict__ Uf, const float* __restrict__ Ub,
    const float* __restrict__ brf, const float* __restrict__ brb,
    const float* __restrict__ h0f, const float* __restrict__ h0b,
    const int* __restrict__ mask, float* __restrict__ out) {
    int b = blockIdx.x & 3;
    int dir = blockIdx.x >> 2;
    const float* __restrict__ xg = dir ? xgb : xgf;
    const float* __restrict__ U = dir ? Ub : Uf;
    const float* __restrict__ br = dir ? brb : brf;
    const float* __restrict__ h0 = dir ? h0b : h0f;
    const int tid = threadIdx.x;  // == column c
    const int gate = tid >> 7;
    const int cp = tid & 127;

    __shared__ __align__(16) float xs[2][16 * 384];
    __shared__ __align__(16) float hsh[128];
    __shared__ float zs[128], rs[128], gxv[128], grv[128];
    __shared__ unsigned long long mwords[8];

    auto stage = [&](int cc, int bufi) {
#pragma unroll
        for (int i = 0; i < 4; i++) {
            int g = i * 384 + tid;       // 16B-group 0..1535
            int j = g / 96;              // step-in-chunk
            int col = (g - j * 96) * 4;
            int ts = cc * 16 + j;
            int t = dir ? (511 - ts) : ts;
            const float* src = xg + ((long)(b * 512 + t)) * 384 + col;
            __builtin_amdgcn_global_load_lds(
                (const __attribute__((address_space(1))) void*)src,
                (__attribute__((address_space(3))) void*)&xs[bufi][g * 4], 16, 0, 0);
        }
    };
    stage(0, 0);

    f32x4 u4[32];
#pragma unroll
    for (int k = 0; k < 32; k++) {
        u4[k].x = U[(k * 4 + 0) * 384 + tid];
        u4[k].y = U[(k * 4 + 1) * 384 + tid];
        u4[k].z = U[(k * 4 + 2) * 384 + tid];
        u4[k].w = U[(k * 4 + 3) * 384 + tid];
    }
#pragma unroll
    for (int k = 0; k < 32; k++) asm volatile("" : "+v"(u4[k]));
    float brv = br[tid];

    float hreg = 0.f;
    if (tid < 128) {
        hreg = h0[b * 128 + tid];
        hsh[tid] = hreg;
    }
    if (tid < 64) {
#pragma unroll
        for (int w = 0; w < 8; w++) {
            int idx = w * 64 + tid;
            int t = dir ? (511 - idx) : idx;
            unsigned long long bm = __ballot(mask[b * 512 + t] != 0);
            if (tid == 0) mwords[w] = bm;
        }
    }
    asm volatile("s_waitcnt lgkmcnt(0)" ::: "memory");
    __builtin_amdgcn_s_barrier();

    for (int cc = 0; cc < 32; cc++) {
        asm volatile("s_waitcnt vmcnt(0)" ::: "memory");
        if (cc < 31) stage(cc + 1, (cc + 1) & 1);
        __builtin_amdgcn_s_barrier();
        __builtin_amdgcn_sched_barrier(0);
        const float* xb = xs[cc & 1];
        unsigned mwbits = (unsigned)((mwords[cc >> 2] >> ((cc & 3) * 16)) & 0xffffull);
#pragma unroll 1
        for (int jj = 0; jj < 16; jj++) {
            int step = cc * 16 + jj;
            int t = dir ? (511 - step) : step;
            long obase = ((long)(b * 512 + t)) * 256 + dir * 128;
            if ((mwbits >> jj) & 1) {
                float xtv = xb[jj * 384 + tid];
                float a0 = 0.f, a1 = 0.f, a2 = 0.f, a3 = 0.f;
#pragma unroll
                for (int k = 0; k < 32; k++) {
                    const float4 hv = *(const float4*)&hsh[k * 4];  // uniform
                    a0 = fmaf(hv.x, u4[k].x, a0);
                    a1 = fmaf(hv.y, u4[k].y, a1);
                    a2 = fmaf(hv.z, u4[k].z, a2);
                    a3 = fmaf(hv.w, u4[k].w, a3);
                }
                float rg = (a0 + a1) + (a2 + a3) + brv;
                if (gate == 0) zs[cp] = sigmoid_fast(xtv + rg);
                else if (gate == 1) rs[cp] = sigmoid_fast(xtv + rg);
                else { gxv[cp] = xtv; grv[cp] = rg; }
                asm volatile("s_waitcnt lgkmcnt(0)" ::: "memory");
                __builtin_amdgcn_s_barrier();
                if (tid < 128) {
                    float z = zs[tid], r_ = rs[tid];
                    float hhv = tanh_fast(fmaf(r_, grv[tid], gxv[tid]));
                    float hn = fmaf(z, hreg - hhv, hhv);
                    hreg = hn;
                    hsh[tid] = hn;
                    out[obase + tid] = hn;
                }
                asm volatile("s_waitcnt lgkmcnt(0)" ::: "memory");
                __builtin_amdgcn_s_barrier();
            } else {
                if (tid < 128) out[obase + tid] = hreg;
            }
        }
    }
}

// final dense 256 -> 1, one wave per row
__global__ __launch_bounds__(256) void final_kernel(
    const float* __restrict__ fc2, const float* __restrict__ w,
    const float* __restrict__ b, float* __restrict__ out) {
    int row = blockIdx.x * 4 + (threadIdx.x >> 6);
    int lane = threadIdx.x & 63;
    const float* a = fc2 + (long)row * 256;
    float acc = 0.f;
#pragma unroll
    for (int i = 0; i < 4; i++) acc = fmaf(a[lane + i * 64], w[lane + i * 64], acc);
#pragma unroll
    for (int off = 32; off; off >>= 1) acc += __shfl_down(acc, off);
    if (lane == 0) out[row] = acc + b[0];
}

// ---------------------------------------------------------------------------
extern "C" void kernel_launch(void* const* d_in, const int* in_sizes, int n_in,
                              void* d_out, int out_size, void* d_ws,
                              size_t ws_size, hipStream_t stream) {
    const float* x = (const float*)d_in[0];
    const unsigned int* mraw = (const unsigned int*)d_in[1];
    const float* s1f = (const float*)d_in[2];
    const float* s1b = (const float*)d_in[3];
    const float* s2f = (const float*)d_in[4];
    const float* s2b = (const float*)d_in[5];
    const float* c1w = (const float*)d_in[6];
    const float* c1b = (const float*)d_in[7];
    const float* c2w = (const float*)d_in[8];
    const float* c2b = (const float*)d_in[9];
    const float* g1fW = (const float*)d_in[10];
    const float* g1fU = (const float*)d_in[11];
    const float* g1fb = (const float*)d_in[12];
    const float* g1bW = (const float*)d_in[13];
    const float* g1bU = (const float*)d_in[14];
    const float* g1bb = (const float*)d_in[15];
    const float* g2fW = (const float*)d_in[16];
    const float* g2fU = (const float*)d_in[17];
    const float* g2fb = (const float*)d_in[18];
    const float* g2bW = (const float*)d_in[19];
    const float* g2bU = (const float*)d_in[20];
    const float* g2bb = (const float*)d_in[21];
    const float* d1w = (const float*)d_in[22];
    const float* d1b = (const float*)d_in[23];
    const float* d2w = (const float*)d_in[24];
    const float* d2b = (const float*)d_in[25];
    const float* d3w = (const float*)d_in[26];
    const float* d3b = (const float*)d_in[27];
    float* out = (float*)d_out;

    float* ws = (float*)d_ws;
    size_t off = 0;
    auto take = [&](size_t n) {
        float* p = ws + off;
        off += (n + 63) & ~(size_t)63;
        return p;
    };
    int* mask_i = (int*)take(2048);
    float* feat = take(2048UL * 1664);
    float* xg1f = take(2048UL * 384);
    float* xg1b = take(2048UL * 384);
    float* gru1 = take(2048UL * 256);
    float* xg2f = take(2048UL * 384);
    float* xg2b = take(2048UL * 384);
    float* gru2 = take(2048UL * 256);
    float* sc = take(4UL * 512 * 512);
    float* attn = take(2048UL * 256);
    float* fc1 = take(2048UL * 256);
    float* fc2 = take(2048UL * 256);
    unsigned short* bth = (unsigned short*)take(65536);
    unsigned short* btl = (unsigned short*)take(65536);
    unsigned short* wt1fh = (unsigned short*)take(319488);  // 384*1664 ushort
    unsigned short* wt1fl = (unsigned short*)take(319488);
    unsigned short* wt1bh = (unsigned short*)take(319488);
    unsigned short* wt1bl = (unsigned short*)take(319488);
    unsigned short* wt2fh = (unsigned short*)take(49152);   // 384*256 ushort
    unsigned short* wt2fl = (unsigned short*)take(49152);
    unsigned short* wt2bh = (unsigned short*)take(49152);
    unsigned short* wt2bl = (unsigned short*)take(49152);

    mask_decode_kernel<<<1, 256, 0, stream>>>(mraw, mask_i);
    prepack_w2<<<512, 256, 0, stream>>>(c2w, bth, btl);
    prepack_wt<<<2496, 256, 0, stream>>>(g1fW, wt1fh, wt1fl, 1664, 384);
    prepack_wt<<<2496, 256, 0, stream>>>(g1bW, wt1bh, wt1bl, 1664, 384);
    prepack_wt<<<384, 256, 0, stream>>>(g2fW, wt2fh, wt2fl, 256, 384);
    prepack_wt<<<384, 256, 0, stream>>>(g2bW, wt2bh, wt2bl, 256, 384);
    conv_kernel<<<2048, 256, 0, stream>>>(x, c1w, c1b, bth, btl, c2b, feat);

    gemm_bf16<0><<<dim3(6, 32), 256, 0, stream>>>(feat, wt1fh, wt1fl, g1fb,
                                                  xg1f, 2048, 384, 1664);
    gemm_bf16<0><<<dim3(6, 32), 256, 0, stream>>>(feat, wt1bh, wt1bl, g1bb,
                                                  xg1b, 2048, 384, 1664);
    gru_kernel<<<8, 384, 0, stream>>>(xg1f, xg1b, g1fU, g1bU, g1fb + 384,
                                      g1bb + 384, s1f, s1b, mask_i, gru1);

    gemm_bf16<0><<<dim3(6, 32), 256, 0, stream>>>(gru1, wt2fh, wt2fl, g2fb,
                                                  xg2f, 2048, 384, 256);
    gemm_bf16<0><<<dim3(6, 32), 256, 0, stream>>>(gru1, wt2bh, wt2bl, g2bb,
                                                  xg2b, 2048, 384, 256);
    gru_kernel<<<8, 384, 0, stream>>>(xg2f, xg2b, g2fU, g2bU, g2fb + 384,
                                      g2bb + 384, s2f, s2b, mask_i, gru2);

    scores_kernel<<<dim3(8, 8, 4), 256, 0, stream>>>(gru2, mask_i, sc);
    softmax_kernel<<<2048, 256, 0, stream>>>(sc);
    gemm_nn<0><<<dim3(4, 8, 4), 256, 0, stream>>>(sc, 512L * 512, gru2, 512L * 256,
                                                  nullptr, mask_i, attn, 512L * 256,
                                                  512, 256, 512);

    gemm_nn<1><<<dim3(4, 32, 1), 256, 0, stream>>>(attn, 0, d1w, 0, d1b, nullptr,
                                                   fc1, 0, 2048, 256, 256);
    gemm_nn<1><<<dim3(4, 32, 1), 256, 0, stream>>>(fc1, 0, d2w, 0, d2b, nullptr,
                                                   fc2, 0, 2048, 256, 256);
    final_kernel<<<512, 256, 0, stream>>>(fc2, d3w, d3b, out);
}

// Round 6
// 774.250 us; speedup vs baseline: 1.7301x; 1.1554x over previous
//
#include <hip/hip_runtime.h>

#define LRELU(v) ((v) > 0.f ? (v) : 0.2f * (v))

typedef float f32x4 __attribute__((ext_vector_type(4)));
typedef __bf16 bf16x8 __attribute__((ext_vector_type(8)));
typedef unsigned short ushort8v __attribute__((ext_vector_type(8)));

__device__ __forceinline__ unsigned short f2bf(float f) {
    unsigned int u = __float_as_uint(f);
    u += 0x7fffu + ((u >> 16) & 1u);
    return (unsigned short)(u >> 16);
}
__device__ __forceinline__ float bf2f(unsigned short h) {
    return __uint_as_float(((unsigned int)h) << 16);
}
__device__ __forceinline__ float sigmoid_fast(float x) {
    float e = __builtin_amdgcn_exp2f(-x * 1.442695041f);
    return __builtin_amdgcn_rcpf(1.f + e);
}
__device__ __forceinline__ float tanh_fast(float x) {
    float e = __builtin_amdgcn_exp2f(x * 2.885390082f);  // e^(2x)
    return 1.f - 2.f * __builtin_amdgcn_rcpf(e + 1.f);
}
// quad_perm DPP adds (VALU pipe - NOT ds_swizzle)
__device__ __forceinline__ float dpp_add_xor1(float v) {
    int r = __builtin_amdgcn_mov_dpp(__float_as_int(v), 0xB1, 0xF, 0xF, true);
    return v + __int_as_float(r);
}
__device__ __forceinline__ float dpp_add_xor2(float v) {
    int r = __builtin_amdgcn_mov_dpp(__float_as_int(v), 0x4E, 0xF, 0xF, true);
    return v + __int_as_float(r);
}

// ---------------------------------------------------------------------------
// mask decode: input may be bool (1B) or int32 (4B). Sniff deterministically.
// ---------------------------------------------------------------------------
__global__ void mask_decode_kernel(const unsigned int* __restrict__ mraw,
                                   int* __restrict__ mi) {
    __shared__ int is_u8;
    if (threadIdx.x == 0) {
        int u8 = 0;
        for (int i = 0; i < 512; i++) {
            if (mraw[i] > 1u) { u8 = 1; break; }
        }
        is_u8 = u8;
    }
    __syncthreads();
    if (is_u8) {
        const unsigned char* b8 = (const unsigned char*)mraw;
        for (int i = threadIdx.x; i < 2048; i += blockDim.x) mi[i] = b8[i] ? 1 : 0;
    } else {
        for (int i = threadIdx.x; i < 2048; i += blockDim.x) mi[i] = mraw[i] ? 1 : 0;
    }
}

// ---------------------------------------------------------------------------
// prepack w2 (8,128,128) -> B^T bf16 hi/lo: Bt[c][k], k = f*128+cin (1024)
// ---------------------------------------------------------------------------
__global__ __launch_bounds__(256) void prepack_w2(const float* __restrict__ w2,
                                                  unsigned short* __restrict__ bth,
                                                  unsigned short* __restrict__ btl) {
    int idx = blockIdx.x * 256 + threadIdx.x;  // 131072 total
    int c = idx >> 10, k = idx & 1023;
    float v = w2[k * 128 + c];
    unsigned short hi = f2bf(v);
    unsigned short lo = f2bf(v - bf2f(hi));
    bth[(long)c * 1024 + k] = hi;
    btl[(long)c * 1024 + k] = lo;
}

// ---------------------------------------------------------------------------
// generic prepack: W (K x N) fp32 -> Wt hi/lo (N x K) bf16
// ---------------------------------------------------------------------------
__global__ __launch_bounds__(256) void prepack_wt(const float* __restrict__ W,
                                                  unsigned short* __restrict__ h,
                                                  unsigned short* __restrict__ l,
                                                  int K, int N) {
    long idx = (long)blockIdx.x * 256 + threadIdx.x;
    if (idx >= (long)K * N) return;
    int n = (int)(idx / K), k = (int)(idx % K);
    float v = W[(long)k * N + n];
    unsigned short hi = f2bf(v);
    unsigned short lo = f2bf(v - bf2f(hi));
    h[idx] = hi;
    l[idx] = lo;
}

// ---------------------------------------------------------------------------
// Fused conv1(fp32)+pool1 -> LDS bf16 hi/lo -> conv2 via split-bf16 MFMA +
// fused leaky+pool2. One block (256 thr, 4 waves) per sequence.
// ---------------------------------------------------------------------------
__global__ __launch_bounds__(256) void conv_kernel(
    const float* __restrict__ x, const float* __restrict__ w1,
    const float* __restrict__ b1, const unsigned short* __restrict__ bth,
    const unsigned short* __restrict__ btl, const float* __restrict__ b2,
    float* __restrict__ feat) {
    __shared__ float xs[3][256];
    __shared__ __align__(16) unsigned short p1h[72 * 128];
    __shared__ __align__(16) unsigned short p1l[72 * 128];
    long s = blockIdx.x;
    int tid = threadIdx.x;
    const float* xp = x + s * 768;
    for (int i = tid; i < 768; i += 256) xs[i % 3][i / 3] = xp[i];
    for (int i = tid; i < 10 * 128; i += 256) {
        p1h[62 * 128 + i] = 0;
        p1l[62 * 128 + i] = 0;
    }
    __syncthreads();

    {   // conv1 + pool1, fp32, swizzled bf16 hi/lo store
        int ch = tid & 127;
        int half = tid >> 7;
        float w1r[24];
#pragma unroll
        for (int fc = 0; fc < 24; fc++) w1r[fc] = w1[fc * 128 + ch];
        float bias1 = b1[ch];
        for (int po = half; po < 62; po += 2) {
            int p0 = po * 4;
            float a0 = bias1, a1 = bias1, a2 = bias1, a3 = bias1;
#pragma unroll
            for (int c = 0; c < 3; c++) {
                float xv[11];
#pragma unroll
                for (int q = 0; q < 11; q++) xv[q] = xs[c][p0 + q];
#pragma unroll
                for (int f = 0; f < 8; f++) {
                    float w = w1r[f * 3 + c];
                    a0 = fmaf(xv[f + 0], w, a0);
                    a1 = fmaf(xv[f + 1], w, a1);
                    a2 = fmaf(xv[f + 2], w, a2);
                    a3 = fmaf(xv[f + 3], w, a3);
                }
            }
            float m01 = fmaxf(LRELU(a0), LRELU(a1));
            float m23 = fmaxf(LRELU(a2), LRELU(a3));
            float v = fmaxf(m01, m23);
            unsigned short hi = f2bf(v);
            unsigned short lo = f2bf(v - bf2f(hi));
            int cs = ch ^ ((po & 7) << 3);
            p1h[po * 128 + cs] = hi;
            p1l[po * 128 + cs] = lo;
        }
    }
    __syncthreads();

    const int l = tid & 63, w = tid >> 6;
    const int r = l & 15, g = l >> 4;
    f32x4 acc[4][2];
    const f32x4 zz = {0.f, 0.f, 0.f, 0.f};
#pragma unroll
    for (int m = 0; m < 4; m++) {
        acc[m][0] = zz;
        acc[m][1] = zz;
    }
#pragma unroll 2
    for (int ks = 0; ks < 32; ks++) {
        const int f = ks >> 2;
        const int cin0 = ((ks & 3) << 5) + (g << 3);
        bf16x8 bh[2], bl[2];
#pragma unroll
        for (int n = 0; n < 2; n++) {
            const int c = ((w << 1) + n) * 16 + r;
            const long bo = (long)c * 1024 + (ks << 5) + (g << 3);
            bh[n] = __builtin_bit_cast(bf16x8, *(const ushort8v*)(bth + bo));
            bl[n] = __builtin_bit_cast(bf16x8, *(const ushort8v*)(btl + bo));
        }
        bf16x8 ah[4], al[4];
#pragma unroll
        for (int m = 0; m < 4; m++) {
            const int row = m * 16 + r + f;
            const int col = cin0 ^ ((row & 7) << 3);
            const int off = row * 128 + col;
            ah[m] = __builtin_bit_cast(bf16x8, *(const ushort8v*)(p1h + off));
            al[m] = __builtin_bit_cast(bf16x8, *(const ushort8v*)(p1l + off));
        }
#pragma unroll
        for (int m = 0; m < 4; m++) {
#pragma unroll
            for (int n = 0; n < 2; n++) {
                acc[m][n] = __builtin_amdgcn_mfma_f32_16x16x32_bf16(ah[m], bh[n], acc[m][n], 0, 0, 0);
                acc[m][n] = __builtin_amdgcn_mfma_f32_16x16x32_bf16(ah[m], bl[n], acc[m][n], 0, 0, 0);
                acc[m][n] = __builtin_amdgcn_mfma_f32_16x16x32_bf16(al[m], bh[n], acc[m][n], 0, 0, 0);
            }
        }
    }
#pragma unroll
    for (int m = 0; m < 4; m++) {
        const int j = m * 4 + g;
        if (j < 13) {
#pragma unroll
            for (int n = 0; n < 2; n++) {
                const int ch = ((w << 1) + n) * 16 + r;
                const float bias = b2[ch];
                float v0 = LRELU(acc[m][n].x + bias);
                float v1 = LRELU(acc[m][n].y + bias);
                float v2 = LRELU(acc[m][n].z + bias);
                float v3 = LRELU(acc[m][n].w + bias);
                feat[s * 1664 + j * 128 + ch] = fmaxf(fmaxf(v0, v1), fmaxf(v2, v3));
            }
        }
    }
}

// ---------------------------------------------------------------------------
// MFMA GEMM: C(M,N) = act(A(M,K,fp32) @ W + bias) using prepacked Wt hi/lo
// (N x K bf16). 64x64 tile, 256 thr / 4 waves, wave w -> 16-col strip.
// ---------------------------------------------------------------------------
template <int ACT>
__global__ __launch_bounds__(256) void gemm_bf16(
    const float* __restrict__ A, const unsigned short* __restrict__ Wth,
    const unsigned short* __restrict__ Wtl, const float* __restrict__ bias,
    float* __restrict__ C, int M, int N, int K) {
    __shared__ __align__(16) unsigned short Ah[64 * 40];
    __shared__ __align__(16) unsigned short Al[64 * 40];
    const int tid = threadIdx.x;
    const int w = tid >> 6, l = tid & 63, r = l & 15, g = l >> 4;
    const int m0 = blockIdx.y * 64, n0 = blockIdx.x * 64;
    const int col = n0 + w * 16 + r;
    const int srow = tid >> 2, sgq = tid & 3;
    f32x4 acc[4];
    const f32x4 zz = {0.f, 0.f, 0.f, 0.f};
#pragma unroll
    for (int m = 0; m < 4; m++) acc[m] = zz;

    const float* ap0 = A + (long)(m0 + srow) * K + sgq * 8;
    const long bbase = (long)col * K + g * 8;
    float4 v0 = *(const float4*)ap0;
    float4 v1 = *(const float4*)(ap0 + 4);
    ushort8v bhc = *(const ushort8v*)(Wth + bbase);
    ushort8v blc = *(const ushort8v*)(Wtl + bbase);

    for (int k0 = 0; k0 < K; k0 += 32) {
        float4 nv0, nv1;
        ushort8v nbh, nbl;
        if (k0 + 32 < K) {
            nv0 = *(const float4*)(ap0 + k0 + 32);
            nv1 = *(const float4*)(ap0 + k0 + 36);
            nbh = *(const ushort8v*)(Wth + bbase + k0 + 32);
            nbl = *(const ushort8v*)(Wtl + bbase + k0 + 32);
        }
        float vv[8] = {v0.x, v0.y, v0.z, v0.w, v1.x, v1.y, v1.z, v1.w};
        ushort8v hh, ll;
#pragma unroll
        for (int q = 0; q < 8; q++) {
            unsigned short h16 = f2bf(vv[q]);
            hh[q] = h16;
            ll[q] = f2bf(vv[q] - bf2f(h16));
        }
        const int slot = sgq ^ (srow & 3);
        __syncthreads();
        *(ushort8v*)&Ah[srow * 40 + slot * 8] = hh;
        *(ushort8v*)&Al[srow * 40 + slot * 8] = ll;
        __syncthreads();
        bf16x8 bh = __builtin_bit_cast(bf16x8, bhc);
        bf16x8 bl = __builtin_bit_cast(bf16x8, blc);
#pragma unroll
        for (int m = 0; m < 4; m++) {
            const int arow = m * 16 + r;
            const int aoff = arow * 40 + ((g ^ (arow & 3)) << 3);
            bf16x8 ah = __builtin_bit_cast(bf16x8, *(const ushort8v*)(Ah + aoff));
            bf16x8 al = __builtin_bit_cast(bf16x8, *(const ushort8v*)(Al + aoff));
            acc[m] = __builtin_amdgcn_mfma_f32_16x16x32_bf16(ah, bh, acc[m], 0, 0, 0);
            acc[m] = __builtin_amdgcn_mfma_f32_16x16x32_bf16(ah, bl, acc[m], 0, 0, 0);
            acc[m] = __builtin_amdgcn_mfma_f32_16x16x32_bf16(al, bh, acc[m], 0, 0, 0);
        }
        v0 = nv0; v1 = nv1; bhc = nbh; blc = nbl;
    }
    const float bv = bias ? bias[col] : 0.f;
#pragma unroll
    for (int m = 0; m < 4; m++) {
#pragma unroll
        for (int q = 0; q < 4; q++) {
            const int row = m0 + m * 16 + g * 4 + q;
            float v = acc[m][q] + bv;
            if (ACT == 1) v = LRELU(v);
            C[(long)row * N + col] = v;
        }
    }
}

// ---------------------------------------------------------------------------
// Generic batched fp32 GEMM: C = act(A @ B + bias) * rowmask
// ---------------------------------------------------------------------------
template <int ACT>
__global__ __launch_bounds__(256) void gemm_nn(
    const float* __restrict__ A, long sA, const float* __restrict__ B, long sB,
    const float* __restrict__ bias, const int* __restrict__ qmask,
    float* __restrict__ C, long sC, int M, int N, int K) {
    int bz = blockIdx.z;
    A += (long)bz * sA;
    B += (long)bz * sB;
    C += (long)bz * sC;
    __shared__ __align__(16) float As[16][68];
    __shared__ __align__(16) float Bs[16][68];
    int tid = threadIdx.x;
    int tm = tid >> 4, tn = tid & 15;
    int m0 = blockIdx.y * 64, n0 = blockIdx.x * 64;
    int la_m = tid & 63, la_k = (tid >> 6) * 4;
    int lb_k = tid >> 4, lb_n = (tid & 15) * 4;
    float acc[4][4] = {};
    for (int k0 = 0; k0 < K; k0 += 16) {
        float4 av = *(const float4*)&A[(long)(m0 + la_m) * K + k0 + la_k];
        float4 bv = *(const float4*)&B[(long)(k0 + lb_k) * N + n0 + lb_n];
        As[la_k + 0][la_m] = av.x;
        As[la_k + 1][la_m] = av.y;
        As[la_k + 2][la_m] = av.z;
        As[la_k + 3][la_m] = av.w;
        *(float4*)&Bs[lb_k][lb_n] = bv;
        __syncthreads();
#pragma unroll
        for (int k = 0; k < 16; k++) {
            float4 a4 = *(const float4*)&As[k][tm * 4];
            float4 b4 = *(const float4*)&Bs[k][tn * 4];
            float aa[4] = {a4.x, a4.y, a4.z, a4.w};
            float bb[4] = {b4.x, b4.y, b4.z, b4.w};
#pragma unroll
            for (int i = 0; i < 4; i++)
#pragma unroll
                for (int j = 0; j < 4; j++) acc[i][j] = fmaf(aa[i], bb[j], acc[i][j]);
        }
        __syncthreads();
    }
#pragma unroll
    for (int i = 0; i < 4; i++) {
        int row = m0 + tm * 4 + i;
        float msc = qmask ? (float)qmask[(long)bz * M + row] : 1.f;
#pragma unroll
        for (int j = 0; j < 4; j++) {
            int col = n0 + tn * 4 + j;
            float v = acc[i][j] + (bias ? bias[col] : 0.f);
            if (ACT == 1) v = LRELU(v);
            C[(long)row * N + col] = v * msc;
        }
    }
}

// ---------------------------------------------------------------------------
// scores = h @ h^T with key-mask (-1e9), batched over 4.
// ---------------------------------------------------------------------------
__global__ __launch_bounds__(256) void scores_kernel(
    const float* __restrict__ h, const int* __restrict__ mask,
    float* __restrict__ S) {
    int bz = blockIdx.z;
    const float* A = h + (long)bz * 512 * 256;
    float* C = S + (long)bz * 512 * 512;
    __shared__ __align__(16) float As[16][68];
    __shared__ __align__(16) float Bs[16][68];
    int tid = threadIdx.x;
    int tm = tid >> 4, tn = tid & 15;
    int m0 = blockIdx.y * 64, n0 = blockIdx.x * 64;
    int lr = tid & 63, lk = (tid >> 6) * 4;
    float acc[4][4] = {};
    for (int k0 = 0; k0 < 256; k0 += 16) {
        float4 av = *(const float4*)&A[(long)(m0 + lr) * 256 + k0 + lk];
        float4 bv = *(const float4*)&A[(long)(n0 + lr) * 256 + k0 + lk];
        As[lk + 0][lr] = av.x;
        As[lk + 1][lr] = av.y;
        As[lk + 2][lr] = av.z;
        As[lk + 3][lr] = av.w;
        Bs[lk + 0][lr] = bv.x;
        Bs[lk + 1][lr] = bv.y;
        Bs[lk + 2][lr] = bv.z;
        Bs[lk + 3][lr] = bv.w;
        __syncthreads();
#pragma unroll
        for (int k = 0; k < 16; k++) {
            float4 a4 = *(const float4*)&As[k][tm * 4];
            float4 b4 = *(const float4*)&Bs[k][tn * 4];
            float aa[4] = {a4.x, a4.y, a4.z, a4.w};
            float bb[4] = {b4.x, b4.y, b4.z, b4.w};
#pragma unroll
            for (int i = 0; i < 4; i++)
#pragma unroll
                for (int j = 0; j < 4; j++) acc[i][j] = fmaf(aa[i], bb[j], acc[i][j]);
        }
        __syncthreads();
    }
#pragma unroll
    for (int i = 0; i < 4; i++) {
        int t = m0 + tm * 4 + i;
#pragma unroll
        for (int j = 0; j < 4; j++) {
            int ss = n0 + tn * 4 + j;
            C[(long)t * 512 + ss] = mask[bz * 512 + ss] ? acc[i][j] : -1e9f;
        }
    }
}

// row softmax over 512, block per row
__global__ __launch_bounds__(256) void softmax_kernel(float* __restrict__ S) {
    long row = blockIdx.x;
    float* p = S + row * 512;
    int tid = threadIdx.x;
    __shared__ float red[8];
    float v0 = p[tid], v1 = p[tid + 256];
    float mx = fmaxf(v0, v1);
#pragma unroll
    for (int off = 32; off; off >>= 1) mx = fmaxf(mx, __shfl_down(mx, off));
    if ((tid & 63) == 0) red[tid >> 6] = mx;
    __syncthreads();
    mx = fmaxf(fmaxf(red[0], red[1]), fmaxf(red[2], red[3]));
    float e0 = expf(v0 - mx), e1 = expf(v1 - mx);
    float sm = e0 + e1;
#pragma unroll
    for (int off = 32; off; off >>= 1) sm += __shfl_down(sm, off);
    if ((tid & 63) == 0) red[4 + (tid >> 6)] = sm;
    __syncthreads();
    float inv = 1.f / (red[4] + red[5] + red[6] + red[7]);
    p[tid] = e0 * inv;
    p[tid + 256] = e1 * inv;
}

// ---------------------------------------------------------------------------
// GRU scan v5. 8 blocks = (batch)x(dir), 512 threads = 8 waves.
// thread = (col c = tid>>2, kquad kq = tid&3). Each thread: ALL 3 gates for
// its 32-k slice (u = 96 VGPRs), reads only 128B of h/step (8x b128 from
// double-buffered, bank-padded hsh). Quad reduce via DPP quad_perm (VALU).
// Lane kq==0 owns the column: computes z,r,cand,hn locally, keeps hreg
// replica (masked steps touch no LDS), writes hsh[next]. ONE barrier per
// active step, none on masked steps. xg staged in 16-step async chunks.
// ---------------------------------------------------------------------------
__global__ __launch_bounds__(512, 2) void gru_kernel(
    const float* __restrict__ xgf, const float* __restrict__ xgb,
    const float* __restrict__ Uf, const float* __restrict__ Ub,
    const float* __restrict__ brf, const float* __restrict__ brb,
    const float* __restrict__ h0f, const float* __restrict__ h0b,
    const int* __restrict__ mask, float* __restrict__ out) {
    int b = blockIdx.x & 3;
    int dir = blockIdx.x >> 2;
    const float* __restrict__ xg = dir ? xgb : xgf;
    const float* __restrict__ U = dir ? Ub : Uf;
    const float* __restrict__ br = dir ? brb : brf;
    const float* __restrict__ h0 = dir ? h0b : h0f;
    const int tid = threadIdx.x;
    const int c = tid >> 2;   // column 0..127
    const int kq = tid & 3;   // k-quad

    __shared__ __align__(16) float xs[2][16 * 384];
    __shared__ __align__(16) float hsh[2][144];  // 36-float chunks per kq (bank pad)
    __shared__ unsigned long long mwords[8];

    auto stage = [&](int cc, int bufi) {
#pragma unroll
        for (int i = 0; i < 3; i++) {
            int g = i * 512 + tid;       // 16B-group 0..1535
            int j = g / 96;              // step-in-chunk
            int col = (g - j * 96) * 4;
            int ts = cc * 16 + j;
            int t = dir ? (511 - ts) : ts;
            const float* src = xg + ((long)(b * 512 + t)) * 384 + col;
            __builtin_amdgcn_global_load_lds(
                (const __attribute__((address_space(1))) void*)src,
                (__attribute__((address_space(3))) void*)&xs[bufi][g * 4], 16, 0, 0);
        }
    };
    stage(0, 0);

    // u4[g][q].i = U[(kq*32 + q*4 + i)*384 + g*128 + c]  (96 VGPRs)
    f32x4 u4[3][8];
#pragma unroll
    for (int g = 0; g < 3; g++)
#pragma unroll
        for (int q = 0; q < 8; q++) {
            const float* up = U + (long)(kq * 32 + q * 4) * 384 + g * 128 + c;
            u4[g][q].x = up[0];
            u4[g][q].y = up[384];
            u4[g][q].z = up[768];
            u4[g][q].w = up[1152];
        }
    float br3[3];
#pragma unroll
    for (int g = 0; g < 3; g++) br3[g] = br[g * 128 + c];

    float hreg = h0[b * 128 + c];
    if (kq == 0) hsh[0][c + (c >> 5) * 4] = hreg;
    if (tid < 64) {
#pragma unroll
        for (int w = 0; w < 8; w++) {
            int idx = w * 64 + tid;
            int t = dir ? (511 - idx) : idx;
            unsigned long long bm = __ballot(mask[b * 512 + t] != 0);
            if (tid == 0) mwords[w] = bm;
        }
    }
    asm volatile("s_waitcnt lgkmcnt(0)" ::: "memory");
    __builtin_amdgcn_s_barrier();

    int cur = 0;
    for (int cc = 0; cc < 32; cc++) {
        asm volatile("s_waitcnt vmcnt(0)" ::: "memory");
        if (cc < 31) stage(cc + 1, (cc + 1) & 1);
#pragma unroll
        for (int g = 0; g < 3; g++)
#pragma unroll
            for (int q = 0; q < 8; q++) asm volatile("" : "+v"(u4[g][q]));
        __builtin_amdgcn_s_barrier();
        const float* xb = xs[cc & 1];
        unsigned mwbits = (unsigned)((mwords[cc >> 2] >> ((cc & 3) * 16)) & 0xffffull);
#pragma unroll 1
        for (int jj = 0; jj < 16; jj++) {
            int step = cc * 16 + jj;
            int t = dir ? (511 - step) : step;
            long obase = ((long)(b * 512 + t)) * 256 + dir * 128;
            if ((mwbits >> jj) & 1) {
                const float* hp = &hsh[cur][kq * 36];
                float az0 = 0.f, az1 = 0.f, ar0 = 0.f, ar1 = 0.f, ah0 = 0.f, ah1 = 0.f;
#pragma unroll
                for (int q = 0; q < 8; q++) {
                    float4 h4 = *(const float4*)(hp + q * 4);
                    az0 = fmaf(h4.x, u4[0][q].x, az0);
                    az1 = fmaf(h4.y, u4[0][q].y, az1);
                    az0 = fmaf(h4.z, u4[0][q].z, az0);
                    az1 = fmaf(h4.w, u4[0][q].w, az1);
                    ar0 = fmaf(h4.x, u4[1][q].x, ar0);
                    ar1 = fmaf(h4.y, u4[1][q].y, ar1);
                    ar0 = fmaf(h4.z, u4[1][q].z, ar0);
                    ar1 = fmaf(h4.w, u4[1][q].w, ar1);
                    ah0 = fmaf(h4.x, u4[2][q].x, ah0);
                    ah1 = fmaf(h4.y, u4[2][q].y, ah1);
                    ah0 = fmaf(h4.z, u4[2][q].z, ah0);
                    ah1 = fmaf(h4.w, u4[2][q].w, ah1);
                }
                float rgz = dpp_add_xor2(dpp_add_xor1(az0 + az1));
                float rgr = dpp_add_xor2(dpp_add_xor1(ar0 + ar1));
                float rgh = dpp_add_xor2(dpp_add_xor1(ah0 + ah1));
                if (kq == 0) {
                    float xz = xb[jj * 384 + c];
                    float xr = xb[jj * 384 + 128 + c];
                    float xh = xb[jj * 384 + 256 + c];
                    float z = sigmoid_fast(xz + rgz + br3[0]);
                    float r_ = sigmoid_fast(xr + rgr + br3[1]);
                    float hc = tanh_fast(fmaf(r_, rgh + br3[2], xh));
                    float hn = fmaf(z, hreg - hc, hc);
                    hreg = hn;
                    hsh[cur ^ 1][c + (c >> 5) * 4] = hn;
                    out[obase + c] = hn;
                }
                asm volatile("s_waitcnt lgkmcnt(0)" ::: "memory");
                __builtin_amdgcn_s_barrier();
                cur ^= 1;
            } else {
                if (kq == 0) out[obase + c] = hreg;
            }
        }
    }
}

// final dense 256 -> 1, one wave per row
__global__ __launch_bounds__(256) void final_kernel(
    const float* __restrict__ fc2, const float* __restrict__ w,
    const float* __restrict__ b, float* __restrict__ out) {
    int row = blockIdx.x * 4 + (threadIdx.x >> 6);
    int lane = threadIdx.x & 63;
    const float* a = fc2 + (long)row * 256;
    float acc = 0.f;
#pragma unroll
    for (int i = 0; i < 4; i++) acc = fmaf(a[lane + i * 64], w[lane + i * 64], acc);
#pragma unroll
    for (int off = 32; off; off >>= 1) acc += __shfl_down(acc, off);
    if (lane == 0) out[row] = acc + b[0];
}

// ---------------------------------------------------------------------------
extern "C" void kernel_launch(void* const* d_in, const int* in_sizes, int n_in,
                              void* d_out, int out_size, void* d_ws,
                              size_t ws_size, hipStream_t stream) {
    const float* x = (const float*)d_in[0];
    const unsigned int* mraw = (const unsigned int*)d_in[1];
    const float* s1f = (const float*)d_in[2];
    const float* s1b = (const float*)d_in[3];
    const float* s2f = (const float*)d_in[4];
    const float* s2b = (const float*)d_in[5];
    const float* c1w = (const float*)d_in[6];
    const float* c1b = (const float*)d_in[7];
    const float* c2w = (const float*)d_in[8];
    const float* c2b = (const float*)d_in[9];
    const float* g1fW = (const float*)d_in[10];
    const float* g1fU = (const float*)d_in[11];
    const float* g1fb = (const float*)d_in[12];
    const float* g1bW = (const float*)d_in[13];
    const float* g1bU = (const float*)d_in[14];
    const float* g1bb = (const float*)d_in[15];
    const float* g2fW = (const float*)d_in[16];
    const float* g2fU = (const float*)d_in[17];
    const float* g2fb = (const float*)d_in[18];
    const float* g2bW = (const float*)d_in[19];
    const float* g2bU = (const float*)d_in[20];
    const float* g2bb = (const float*)d_in[21];
    const float* d1w = (const float*)d_in[22];
    const float* d1b = (const float*)d_in[23];
    const float* d2w = (const float*)d_in[24];
    const float* d2b = (const float*)d_in[25];
    const float* d3w = (const float*)d_in[26];
    const float* d3b = (const float*)d_in[27];
    float* out = (float*)d_out;

    float* ws = (float*)d_ws;
    size_t off = 0;
    auto take = [&](size_t n) {
        float* p = ws + off;
        off += (n + 63) & ~(size_t)63;
        return p;
    };
    int* mask_i = (int*)take(2048);
    float* feat = take(2048UL * 1664);
    float* xg1f = take(2048UL * 384);
    float* xg1b = take(2048UL * 384);
    float* gru1 = take(2048UL * 256);
    float* xg2f = take(2048UL * 384);
    float* xg2b = take(2048UL * 384);
    float* gru2 = take(2048UL * 256);
    float* sc = take(4UL * 512 * 512);
    float* attn = take(2048UL * 256);
    float* fc1 = take(2048UL * 256);
    float* fc2 = take(2048UL * 256);
    unsigned short* bth = (unsigned short*)take(65536);
    unsigned short* btl = (unsigned short*)take(65536);
    unsigned short* wt1fh = (unsigned short*)take(319488);  // 384*1664 ushort
    unsigned short* wt1fl = (unsigned short*)take(319488);
    unsigned short* wt1bh = (unsigned short*)take(319488);
    unsigned short* wt1bl = (unsigned short*)take(319488);
    unsigned short* wt2fh = (unsigned short*)take(49152);   // 384*256 ushort
    unsigned short* wt2fl = (unsigned short*)take(49152);
    unsigned short* wt2bh = (unsigned short*)take(49152);
    unsigned short* wt2bl = (unsigned short*)take(49152);

    mask_decode_kernel<<<1, 256, 0, stream>>>(mraw, mask_i);
    prepack_w2<<<512, 256, 0, stream>>>(c2w, bth, btl);
    prepack_wt<<<2496, 256, 0, stream>>>(g1fW, wt1fh, wt1fl, 1664, 384);
    prepack_wt<<<2496, 256, 0, stream>>>(g1bW, wt1bh, wt1bl, 1664, 384);
    prepack_wt<<<384, 256, 0, stream>>>(g2fW, wt2fh, wt2fl, 256, 384);
    prepack_wt<<<384, 256, 0, stream>>>(g2bW, wt2bh, wt2bl, 256, 384);
    conv_kernel<<<2048, 256, 0, stream>>>(x, c1w, c1b, bth, btl, c2b, feat);

    gemm_bf16<0><<<dim3(6, 32), 256, 0, stream>>>(feat, wt1fh, wt1fl, g1fb,
                                                  xg1f, 2048, 384, 1664);
    gemm_bf16<0><<<dim3(6, 32), 256, 0, stream>>>(feat, wt1bh, wt1bl, g1bb,
                                                  xg1b, 2048, 384, 1664);
    gru_kernel<<<8, 512, 0, stream>>>(xg1f, xg1b, g1fU, g1bU, g1fb + 384,
                                      g1bb + 384, s1f, s1b, mask_i, gru1);

    gemm_bf16<0><<<dim3(6, 32), 256, 0, stream>>>(gru1, wt2fh, wt2fl, g2fb,
                                                  xg2f, 2048, 384, 256);
    gemm_bf16<0><<<dim3(6, 32), 256, 0, stream>>>(gru1, wt2bh, wt2bl, g2bb,
                                                  xg2b, 2048, 384, 256);
    gru_kernel<<<8, 512, 0, stream>>>(xg2f, xg2b, g2fU, g2bU, g2fb + 384,
                                      g2bb + 384, s2f, s2b, mask_i, gru2);

    scores_kernel<<<dim3(8, 8, 4), 256, 0, stream>>>(gru2, mask_i, sc);
    softmax_kernel<<<2048, 256, 0, stream>>>(sc);
    gemm_nn<0><<<dim3(4, 8, 4), 256, 0, stream>>>(sc, 512L * 512, gru2, 512L * 256,
                                                  nullptr, mask_i, attn, 512L * 256,
                                                  512, 256, 512);

    gemm_nn<1><<<dim3(4, 32, 1), 256, 0, stream>>>(attn, 0, d1w, 0, d1b, nullptr,
                                                   fc1, 0, 2048, 256, 256);
    gemm_nn<1><<<dim3(4, 32, 1), 256, 0, stream>>>(fc1, 0, d2w, 0, d2b, nullptr,
                                                   fc2, 0, 2048, 256, 256);
    final_kernel<<<512, 256, 0, stream>>>(fc2, d3w, d3b, out);
}